// Round 3
// baseline (4988.958 us; speedup 1.0000x reference)
//
#include <hip/hip_runtime.h>
#include <cstdint>
#include <cstddef>

#define N_ 46080
#define B_ 64
#define BLKG 720
#define E_ 400000
#define CX_ 128
#define CE_ 32
#define BNEPS_ 1e-5f
#define CC_ITERS_ 40
#define BITW 24   // words of presence bitmask (768 bits >= 720)
#define SCAN_B 1024

static inline int gr(int n, int b) { return (n + b - 1) / b; }

// ---------------- CSR / reverse-edge ----------------

__global__ void k_rowptr(const int* __restrict__ row, int* __restrict__ rp) {
  int n = blockIdx.x * blockDim.x + threadIdx.x;
  if (n > N_) return;
  int lo = 0, hi = E_;
  while (lo < hi) { int mid = (lo + hi) >> 1; if (row[mid] < n) lo = mid + 1; else hi = mid; }
  rp[n] = lo;
}

__global__ void k_pos(const int* __restrict__ row, const int* __restrict__ col,
                      int* __restrict__ pos) {
  int e = blockIdx.x * blockDim.x + threadIdx.x;
  if (e >= E_) return;
  long long target = (long long)col[e] * N_ + row[e];
  int lo = 0, hi = E_ - 1;
  while (lo < hi) {
    int mid = (lo + hi) >> 1;
    long long k = (long long)row[mid] * N_ + col[mid];
    if (k < target) lo = mid + 1; else hi = mid;
  }
  pos[e] = lo;
}

__global__ void k_tgt(const float* __restrict__ attr, const int* __restrict__ pos,
                      const int* __restrict__ rp, float* __restrict__ tgt) {
  int t = blockIdx.x * blockDim.x + threadIdx.x;
  if (t >= N_ * CE_) return;
  int n = t / CE_, k = t % CE_;
  float s = 0.f;
  int b = rp[n], e = rp[n + 1];
  for (int i = b; i < e; i++) s += attr[(size_t)pos[i] * CE_ + k];
  tgt[t] = s;
}

__global__ void k_eaprop(const float* __restrict__ attr, const float* __restrict__ tgt,
                         const int* __restrict__ row, float* __restrict__ A) {
  int t = blockIdx.x * blockDim.x + threadIdx.x;
  if (t >= E_ * CE_) return;
  int e = t / CE_, k = t % CE_;
  A[t] = tgt[row[e] * CE_ + k] + attr[t];
}

// ---------------- mlp_e: Linear(32->32) + BN(train) + ReLU ----------------

__global__ void k_mlp(const float* __restrict__ A, const float* __restrict__ We,
                      const float* __restrict__ be, float* __restrict__ H) {
  __shared__ float sWe[CE_ * CE_];
  __shared__ float sA[8 * CE_];
  int t = threadIdx.x;
  for (int i = t; i < CE_ * CE_; i += 256) sWe[i] = We[i];
  int e0 = blockIdx.x * 8;
  for (int i = t; i < 8 * CE_; i += 256) sA[i] = A[(size_t)e0 * CE_ + i];
  __syncthreads();
  int el = t >> 5, j = t & 31;
  float acc = be[j];
  for (int k = 0; k < CE_; k++) acc += sA[el * CE_ + k] * sWe[k * CE_ + j];
  H[(size_t)(e0 + el) * CE_ + j] = acc;
}

__global__ void k_bnstats(const float* __restrict__ H, double* __restrict__ acc) {
  int t = threadIdx.x; int ch = t & 31, grp = t >> 5;
  double s = 0.0, s2 = 0.0;
  for (int e = blockIdx.x * 8 + grp; e < E_; e += gridDim.x * 8) {
    double v = H[(size_t)e * CE_ + ch];
    s += v; s2 += v * v;
  }
  __shared__ double sh[256], sh2[256];
  sh[t] = s; sh2[t] = s2; __syncthreads();
  for (int off = 128; off >= 32; off >>= 1) {
    if (t < off) { sh[t] += sh[t + off]; sh2[t] += sh2[t + off]; }
    __syncthreads();
  }
  if (t < 32) { atomicAdd(&acc[ch], sh[t]); atomicAdd(&acc[32 + ch], sh2[t]); }
}

__global__ void k_bnfin(const double* __restrict__ acc, const float* __restrict__ g,
                        const float* __restrict__ b, const float* __restrict__ S,
                        float* __restrict__ scale, float* __restrict__ shift,
                        float* __restrict__ snorm) {
  int t = threadIdx.x;
  if (t < CE_) {
    double mu = acc[t] / (double)E_;
    double var = acc[32 + t] / (double)E_ - mu * mu;
    float sc = (float)((double)g[t] / sqrt(var + 1e-5));
    scale[t] = sc;
    shift[t] = b[t] - (float)mu * sc;
  }
  if (t == 0) {
    float s = 0.f;
    for (int k = 0; k < CE_; k++) s += S[k] * S[k];
    *snorm = sqrtf(s);
  }
}

__global__ void k_bnapply(const float* __restrict__ H, const float* __restrict__ scale,
                          const float* __restrict__ shift, float* __restrict__ A) {
  int t = blockIdx.x * blockDim.x + threadIdx.x;
  if (t >= E_ * CE_) return;
  int k = t & 31;
  float v = H[t] * scale[k] + shift[k];
  A[t] = v > 0.f ? v : 0.f;
}

// ---------------- edge score / selection ----------------

__global__ void k_tdot(const float* __restrict__ A, const float* __restrict__ S,
                       float* __restrict__ tdot) {
  __shared__ float sS[CE_];
  if (threadIdx.x < CE_) sS[threadIdx.x] = S[threadIdx.x];
  __syncthreads();
  int e = blockIdx.x * blockDim.x + threadIdx.x;
  if (e >= E_) return;
  const float4* a4 = (const float4*)(A + (size_t)e * CE_);
  float s = 0.f;
  for (int q = 0; q < 8; q++) {
    float4 v = a4[q];
    s += v.x * sS[q * 4 + 0] + v.y * sS[q * 4 + 1] + v.z * sS[q * 4 + 2] + v.w * sS[q * 4 + 3];
  }
  tdot[e] = s;
}

__global__ void k_score(const float* __restrict__ tdot, const int* __restrict__ pos,
                        const float* __restrict__ snorm, float* __restrict__ score) {
  int e = blockIdx.x * blockDim.x + threadIdx.x;
  if (e >= E_) return;
  float z = (tdot[e] + tdot[pos[e]]) / (*snorm);
  score[e] = 1.f / (1.f + expf(-z));
}

__global__ void k_gmean(const float* __restrict__ score, const int* __restrict__ rp,
                        float* __restrict__ gmean) {
  int g = blockIdx.x; int t = threadIdx.x;
  int b = rp[g * BLKG], e = rp[(g + 1) * BLKG];
  float s = 0.f;
  for (int i = b + t; i < e; i += 256) s += score[i];
  __shared__ float sh[256];
  sh[t] = s; __syncthreads();
  for (int off = 128; off; off >>= 1) { if (t < off) sh[t] += sh[t + off]; __syncthreads(); }
  if (t == 0) gmean[g] = sh[0] / (float)(e - b);
}

__global__ void k_sel(const float* __restrict__ score, const float* __restrict__ gmean,
                      const int* __restrict__ row,
                      int* __restrict__ sel, int* __restrict__ xmask) {
  int e = blockIdx.x * blockDim.x + threadIdx.x;
  if (e >= E_) return;
  int r = row[e];
  int g = r / BLKG;
  float s = score[e];
  int v = (s <= 0.5f) && (s < gmean[g]);
  sel[e] = v;
  if (v) atomicOr(&xmask[r], 1);
}

__global__ void k_ea3(float* __restrict__ A, const float* __restrict__ score) {
  int t = blockIdx.x * blockDim.x + threadIdx.x;
  if (t >= E_ * CE_) return;
  A[t] *= score[t >> 5];
}

// ---------------- connected components: fused, one block per graph ----------------
// Edges never cross 720-node graph blocks, so all 40 reference iterations run
// block-locally in LDS with exact integer semantics (min step + cur^4 jump).

__global__ __launch_bounds__(256) void k_cc(const int* __restrict__ rp,
                                            const int* __restrict__ row,
                                            const int* __restrict__ col,
                                            const int* __restrict__ sel,
                                            int* __restrict__ lab_g) {
  __shared__ int lab[BLKG], cur[BLKG];
  int g = blockIdx.x, t = threadIdx.x;
  int base = g * BLKG;
  int e0 = rp[base], e1 = rp[base + BLKG];
  for (int i = t; i < BLKG; i += 256) lab[i] = i;
  __syncthreads();
  for (int it = 0; it < CC_ITERS_; ++it) {
    for (int i = t; i < BLKG; i += 256) cur[i] = lab[i];
    __syncthreads();
    for (int e = e0 + t; e < e1; e += 256) {
      if (sel[e]) {
        int r = row[e] - base, c = col[e] - base;
        atomicMin(&cur[r], lab[c]);
        atomicMin(&cur[c], lab[r]);
      }
    }
    __syncthreads();
    for (int i = t; i < BLKG; i += 256) {
      int v = cur[i]; v = cur[v]; v = cur[v]; v = cur[v];  // m=m[m]; m=m[m]
      lab[i] = v;
    }
    __syncthreads();
  }
  for (int i = t; i < BLKG; i += 256) lab_g[base + i] = base + lab[i];
}

__global__ void k_isrep(const int* __restrict__ lab, int* __restrict__ cum) {
  int n = blockIdx.x * blockDim.x + threadIdx.x;
  if (n < N_) cum[n] = (lab[n] == n) ? 1 : 0;
}

// ---------------- multi-block inclusive scan ----------------

__global__ void k_scan1(int* __restrict__ d, int* __restrict__ parts, int n) {
  __shared__ int s[SCAN_B];
  int i = blockIdx.x * SCAN_B + threadIdx.x;
  int v = (i < n) ? d[i] : 0;
  s[threadIdx.x] = v; __syncthreads();
  for (int off = 1; off < SCAN_B; off <<= 1) {
    int t2 = (threadIdx.x >= off) ? s[threadIdx.x - off] : 0;
    __syncthreads();
    s[threadIdx.x] += t2;
    __syncthreads();
  }
  if (i < n) d[i] = s[threadIdx.x];
  if (threadIdx.x == SCAN_B - 1) parts[blockIdx.x] = s[SCAN_B - 1];
}

__global__ void k_scan2(int* __restrict__ parts, int nb) {
  __shared__ int s[SCAN_B];
  int v = ((int)threadIdx.x < nb) ? parts[threadIdx.x] : 0;
  s[threadIdx.x] = v; __syncthreads();
  for (int off = 1; off < SCAN_B; off <<= 1) {
    int t2 = (threadIdx.x >= off) ? s[threadIdx.x - off] : 0;
    __syncthreads();
    s[threadIdx.x] += t2;
    __syncthreads();
  }
  if ((int)threadIdx.x < nb) parts[threadIdx.x] = s[threadIdx.x];
}

__global__ void k_scan3(int* __restrict__ d, const int* __restrict__ parts, int n) {
  int i = blockIdx.x * SCAN_B + threadIdx.x;
  if (i < n && blockIdx.x > 0) d[i] += parts[blockIdx.x - 1];
}

// ---------------- comp / counts ----------------

__global__ void k_crep(const int* __restrict__ cum, int* __restrict__ crep) {
  int g = threadIdx.x;
  if (g <= B_) crep[g] = (g == 0) ? 0 : cum[g * BLKG - 1];
}

__global__ void k_comp(const int* __restrict__ cum, const int* __restrict__ lab,
                       int* __restrict__ comp) {
  int n = blockIdx.x * blockDim.x + threadIdx.x;
  if (n < N_) comp[n] = cum[lab[n]] - 1;
}

__global__ void k_cnt(const int* __restrict__ comp, const int* __restrict__ batch,
                      const int* __restrict__ xmask, int* __restrict__ cnt,
                      int* __restrict__ bsum, int* __restrict__ keep) {
  int n = blockIdx.x * blockDim.x + threadIdx.x;
  if (n >= N_) return;
  int c = comp[n];
  atomicAdd(&cnt[c], 1);
  atomicAdd(&bsum[c], batch[n]);
  if (!xmask[n]) atomicAdd(&keep[c], 1);
}

__global__ void k_batchout(const int* __restrict__ cnt, const int* __restrict__ bsum,
                           float* __restrict__ bout) {
  int c = blockIdx.x * blockDim.x + threadIdx.x;
  if (c >= N_) return;
  int ct = cnt[c];
  bout[c] = (float)(bsum[c] / (ct > 0 ? ct : 1));
}

// ---------------- EGIN conv ----------------

__global__ void k_agg(const float* __restrict__ x, const float* __restrict__ A,
                      const int* __restrict__ col, const int* __restrict__ rp,
                      const int* __restrict__ sel, const float* __restrict__ W_edge,
                      const float* __restrict__ epsp, float* __restrict__ hc) {
  __shared__ float sW[CE_ * CX_];
  __shared__ float sea[CE_];
  int n = blockIdx.x, t = threadIdx.x;  // 128 threads
  for (int i = t; i < CE_ * CX_; i += 128) sW[i] = W_edge[i];
  float acc = 0.f;
  int b = rp[n], e = rp[n + 1];
  for (int i = b; i < e; i++) {
    if (!sel[i]) continue;
    __syncthreads();
    if (t < CE_) sea[t] = A[(size_t)i * CE_ + t];
    __syncthreads();
    float m = x[(size_t)col[i] * CX_ + t];
    for (int k = 0; k < CE_; k++) m += sea[k] * sW[k * CX_ + t];
    acc += fmaxf(m, 0.f);
  }
  hc[(size_t)n * CX_ + t] = (1.f + epsp[0]) * x[(size_t)n * CX_ + t] + acc;
}

template <bool RELU>
__global__ void k_gemm128(const float* __restrict__ X, const float* __restrict__ W,
                          const float* __restrict__ bias, float* __restrict__ Y) {
  __shared__ float sX[16 * CX_];
  int t = threadIdx.x;
  int r0 = blockIdx.x * 16;
  for (int i = t; i < 16 * CX_; i += 256) sX[i] = X[(size_t)r0 * CX_ + i];
  __syncthreads();
  int j = t & 127, rl = t >> 7;
  float acc[8];
  for (int i = 0; i < 8; i++) acc[i] = 0.f;
  for (int k = 0; k < CX_; k++) {
    float w = W[k * CX_ + j];
    for (int i = 0; i < 8; i++) acc[i] += sX[(rl + 2 * i) * CX_ + k] * w;
  }
  float b = bias[j];
  for (int i = 0; i < 8; i++) {
    float v = acc[i] + b;
    if (RELU) v = fmaxf(v, 0.f);
    Y[(size_t)(r0 + rl + 2 * i) * CX_ + j] = v;
  }
}

// ---------------- pooling: bitmask gather (no float atomics) ----------------

__global__ void k_nbits(const int* __restrict__ comp, unsigned int* __restrict__ nbits) {
  int n = blockIdx.x * blockDim.x + threadIdx.x;
  if (n >= N_) return;
  int c = comp[n];
  int j = n % BLKG;
  atomicOr(&nbits[(size_t)c * BITW + (j >> 5)], 1u << (j & 31));
}

__global__ void k_pool_g(const float* __restrict__ xc, const float* __restrict__ x,
                         const unsigned int* __restrict__ nbits,
                         const int* __restrict__ cnt, const int* __restrict__ bsum,
                         const int* __restrict__ xmask, const int* __restrict__ keep,
                         float* __restrict__ xout) {
  int t = blockIdx.x * blockDim.x + threadIdx.x;
  if (t >= N_ * CX_) return;
  int c = t >> 7, ch = t & 127;
  int ct = cnt[c];
  float sa = 0.f, sp = 0.f;
  if (ct > 0) {
    int g = bsum[c] / ct;
    int nb = g * BLKG;
    for (int w = 0; w < BITW; w++) {
      unsigned int word = nbits[(size_t)c * BITW + w];
      while (word) {
        int j = __ffs(word) - 1; word &= word - 1;
        int n = nb + w * 32 + j;
        if (xmask[n]) sa += xc[(size_t)n * CX_ + ch];
        else          sp += x[(size_t)n * CX_ + ch];
      }
    }
  }
  xout[t] = (keep[c] > 0) ? sp : sa;
}

// ---------------- edge coalesce (sort-free grouping + gather) ----------------

__global__ void k_fillm1(float* __restrict__ p, int n) {
  int t = blockIdx.x * blockDim.x + threadIdx.x;
  if (t < n) p[t] = -1.0f;
}

__global__ void k_presbits(const int* __restrict__ row, const int* __restrict__ col,
                           const int* __restrict__ sel, const int* __restrict__ comp,
                           const int* __restrict__ crep, unsigned int* __restrict__ bits) {
  int e = blockIdx.x * blockDim.x + threadIdx.x;
  if (e >= E_ || sel[e]) return;
  int cu = comp[row[e]], cv = comp[col[e]];
  int g = row[e] / BLKG;
  int j = cv - crep[g];
  atomicOr(&bits[(size_t)cu * BITW + (j >> 5)], 1u << (j & 31));
}

__global__ void k_dcount(const unsigned int* __restrict__ bits, int* __restrict__ dscan) {
  int cu = blockIdx.x * blockDim.x + threadIdx.x;
  if (cu >= N_) return;
  int s = 0;
  for (int w = 0; w < BITW; w++) s += __popc(bits[(size_t)cu * BITW + w]);
  dscan[cu] = s;
}

__global__ void k_grank(const int* __restrict__ row, const int* __restrict__ col,
                        const int* __restrict__ sel, const int* __restrict__ comp,
                        const int* __restrict__ crep, const unsigned int* __restrict__ bits,
                        const int* __restrict__ dscan, int* __restrict__ grank) {
  int e = blockIdx.x * blockDim.x + threadIdx.x;
  if (e >= E_) return;
  if (sel[e]) { grank[e] = -1; return; }
  int cu = comp[row[e]], cv = comp[col[e]];
  int g = row[e] / BLKG;
  int j = cv - crep[g];
  int base = (cu > 0) ? dscan[cu - 1] : 0;
  int r = 0, wj = j >> 5;
  for (int w = 0; w < wj; w++) r += __popc(bits[(size_t)cu * BITW + w]);
  unsigned int mask = (1u << (j & 31)) - 1u;
  r += __popc(bits[(size_t)cu * BITW + wj] & mask);
  grank[e] = base + r;
}

__global__ void k_gcount(const int* __restrict__ grank, int* __restrict__ gcnt,
                         int* __restrict__ rloc) {
  int e = blockIdx.x * blockDim.x + threadIdx.x;
  if (e >= E_) return;
  int s = grank[e];
  rloc[e] = (s >= 0) ? atomicAdd(&gcnt[s], 1) : -1;
}

__global__ void k_gscatter(const int* __restrict__ grank, const int* __restrict__ goff,
                           const int* __restrict__ rloc, int* __restrict__ eord) {
  int e = blockIdx.x * blockDim.x + threadIdx.x;
  if (e >= E_) return;
  int s = grank[e];
  if (s < 0) return;
  int base = (s > 0) ? goff[s - 1] : 0;
  eord[base + rloc[e]] = e;
}

__global__ void k_attr_g(const float* __restrict__ A, const int* __restrict__ goff,
                         const int* __restrict__ eord, const int* __restrict__ dscan,
                         float* __restrict__ attr_out) {
  int t = blockIdx.x * blockDim.x + threadIdx.x;
  if (t >= E_ * CE_) return;
  int s = t >> 5, k = t & 31;
  int total = dscan[N_ - 1];
  if (s >= total) return;  // padded rows stay zero (memset)
  int base = (s > 0) ? goff[s - 1] : 0;
  int end = goff[s];
  float acc = 0.f;
  for (int i = base; i < end; i++) acc += A[(size_t)eord[i] * CE_ + k];
  attr_out[(size_t)s * CE_ + k] = acc;
}

__global__ void k_eidx(const unsigned int* __restrict__ bits, const int* __restrict__ dscan,
                       const int* __restrict__ cnt, const int* __restrict__ bsum,
                       const int* __restrict__ crep, float* __restrict__ ei0,
                       float* __restrict__ ei1) {
  int cu = blockIdx.x * blockDim.x + threadIdx.x;
  if (cu >= N_) return;
  int base = (cu > 0) ? dscan[cu - 1] : 0;
  int ct = cnt[cu];
  int g = bsum[cu] / (ct > 0 ? ct : 1);
  int cb = crep[g];
  int r = 0;
  for (int w = 0; w < BITW; w++) {
    unsigned int word = bits[(size_t)cu * BITW + w];
    while (word) {
      int bitj = __ffs(word) - 1;
      int j = w * 32 + bitj;
      ei0[base + r] = (float)cu;
      ei1[base + r] = (float)(cb + j);
      r++;
      word &= word - 1;
    }
  }
}

// ---------------- global pool + BN ----------------

__global__ void k_xg(const float* __restrict__ xout, const int* __restrict__ crep,
                     float* __restrict__ xg_raw) {
  int b = blockIdx.x, ch = threadIdx.x;
  float s = 0.f;
  int c0 = crep[b], c1 = crep[b + 1];
  for (int c = c0; c < c1; c++) s += xout[(size_t)c * CX_ + ch];
  xg_raw[b * CX_ + ch] = s;
}

__global__ void k_xgbn(const float* __restrict__ xg_raw, const float* __restrict__ g,
                       const float* __restrict__ bb, float* __restrict__ xg) {
  int ch = threadIdx.x;
  float mu = 0.f;
  for (int b = 0; b < B_; b++) mu += xg_raw[b * CX_ + ch];
  mu /= (float)B_;
  float var = 0.f;
  for (int b = 0; b < B_; b++) { float d = xg_raw[b * CX_ + ch] - mu; var += d * d; }
  var /= (float)B_;
  float sc = g[ch] / sqrtf(var + BNEPS_);
  for (int b = 0; b < B_; b++)
    xg[b * CX_ + ch] = (xg_raw[b * CX_ + ch] - mu) * sc + bb[ch];
}

// ---------------- launch ----------------

extern "C" void kernel_launch(void* const* d_in, const int* in_sizes, int n_in,
                              void* d_out, int out_size, void* d_ws, size_t ws_size,
                              hipStream_t stream) {
  const float* x      = (const float*)d_in[0];
  const int*   ei     = (const int*)d_in[1];
  const int*   row    = ei;
  const int*   col    = ei + E_;
  const float* eattr  = (const float*)d_in[2];
  const int*   batch  = (const int*)d_in[3];
  const float* S      = (const float*)d_in[4];
  const float* We     = (const float*)d_in[5];
  const float* be     = (const float*)d_in[6];
  const float* bn_e_g = (const float*)d_in[7];
  const float* bn_e_b = (const float*)d_in[8];
  const float* W_edge = (const float*)d_in[9];
  const float* epsp   = (const float*)d_in[10];
  const float* W1     = (const float*)d_in[11];
  const float* b1     = (const float*)d_in[12];
  const float* W2     = (const float*)d_in[13];
  const float* b2     = (const float*)d_in[14];
  const float* bn_g   = (const float*)d_in[15];
  const float* bn_b   = (const float*)d_in[16];

  float* xout     = (float*)d_out;
  float* ei0      = (float*)d_out + (size_t)N_ * CX_;
  float* ei1      = ei0 + E_;
  float* attr_out = (float*)d_out + (size_t)N_ * CX_ + 2 * (size_t)E_;
  float* bout     = (float*)d_out + (size_t)N_ * CX_ + 2 * (size_t)E_ + (size_t)E_ * CE_;
  float* xg       = (float*)d_out + (size_t)N_ * CX_ + 2 * (size_t)E_ + (size_t)E_ * CE_ + N_;

  char* w = (char*)d_ws;
  size_t off = 0;
  auto alloc = [&](size_t bytes) -> void* {
    void* p = w + off;
    off += (bytes + 511) & ~(size_t)511;
    return p;
  };
  double* bnacc = (double*)alloc(64 * 8);
  float* A      = (float*)alloc((size_t)E_ * CE_ * 4);
  float* Hb     = (float*)alloc((size_t)E_ * CE_ * 4);
  float* tgt    = (float*)alloc((size_t)N_ * CE_ * 4);
  float* hc     = (float*)alloc((size_t)N_ * CX_ * 4);
  float* h1     = (float*)alloc((size_t)N_ * CX_ * 4);
  int*   pos    = (int*)alloc((size_t)E_ * 4);   // later reused as grank
  float* tdot   = (float*)alloc((size_t)E_ * 4);
  float* score  = (float*)alloc((size_t)E_ * 4);
  int*   sel    = (int*)alloc((size_t)E_ * 4);
  int*   gcnt   = (int*)alloc((size_t)E_ * 4);
  int*   rloc   = (int*)alloc((size_t)E_ * 4);
  int*   eord   = (int*)alloc((size_t)E_ * 4);
  int*   rp     = (int*)alloc((size_t)(N_ + 1) * 4);
  int*   cum    = (int*)alloc((size_t)N_ * 4);
  int*   comp   = (int*)alloc((size_t)N_ * 4);
  int*   lab    = (int*)alloc((size_t)N_ * 4);
  int*   cnt    = (int*)alloc((size_t)N_ * 4);
  int*   bsum   = (int*)alloc((size_t)N_ * 4);
  int*   keep   = (int*)alloc((size_t)N_ * 4);
  int*   xmask  = (int*)alloc((size_t)N_ * 4);
  int*   dscan  = (int*)alloc((size_t)N_ * 4);
  unsigned int* bits  = (unsigned int*)alloc((size_t)N_ * BITW * 4);
  unsigned int* nbits = (unsigned int*)alloc((size_t)N_ * BITW * 4);
  int*   parts  = (int*)alloc(1024 * 4);
  int*   crep   = (int*)alloc((size_t)(B_ + 1) * 4);
  float* gmean  = (float*)alloc((size_t)B_ * 4);
  float* xg_raw = (float*)alloc((size_t)B_ * CX_ * 4);
  float* scale  = (float*)alloc(CE_ * 4);
  float* shift  = (float*)alloc(CE_ * 4);
  float* snorm  = (float*)alloc(4);
  if (off > ws_size) return;

  const int NB_N = gr(N_, SCAN_B);   // 45
  const int NB_E = gr(E_, SCAN_B);   // 391

  // ---- zero/init ----
  hipMemsetAsync(bnacc, 0, 64 * 8, stream);
  hipMemsetAsync(cnt, 0, (size_t)N_ * 4, stream);
  hipMemsetAsync(bsum, 0, (size_t)N_ * 4, stream);
  hipMemsetAsync(keep, 0, (size_t)N_ * 4, stream);
  hipMemsetAsync(xmask, 0, (size_t)N_ * 4, stream);
  hipMemsetAsync(bits, 0, (size_t)N_ * BITW * 4, stream);
  hipMemsetAsync(nbits, 0, (size_t)N_ * BITW * 4, stream);
  hipMemsetAsync(gcnt, 0, (size_t)E_ * 4, stream);
  hipMemsetAsync(attr_out, 0, (size_t)E_ * CE_ * 4, stream);
  k_fillm1<<<gr(2 * E_, 256), 256, 0, stream>>>(ei0, 2 * E_);

  // ---- edge prop + mlp_e ----
  k_rowptr<<<gr(N_ + 1, 256), 256, 0, stream>>>(row, rp);
  k_pos<<<gr(E_, 256), 256, 0, stream>>>(row, col, pos);
  k_tgt<<<gr(N_ * CE_, 256), 256, 0, stream>>>(eattr, pos, rp, tgt);
  k_eaprop<<<gr(E_ * CE_, 256), 256, 0, stream>>>(eattr, tgt, row, A);

  k_mlp<<<E_ / 8, 256, 0, stream>>>(A, We, be, Hb);
  k_bnstats<<<512, 256, 0, stream>>>(Hb, bnacc);
  k_bnfin<<<1, 64, 0, stream>>>(bnacc, bn_e_g, bn_e_b, S, scale, shift, snorm);
  k_bnapply<<<gr(E_ * CE_, 256), 256, 0, stream>>>(Hb, scale, shift, A);

  // ---- score / selection ----
  k_tdot<<<gr(E_, 256), 256, 0, stream>>>(A, S, tdot);
  k_score<<<gr(E_, 256), 256, 0, stream>>>(tdot, pos, snorm, score);
  k_gmean<<<B_, 256, 0, stream>>>(score, rp, gmean);
  k_sel<<<gr(E_, 256), 256, 0, stream>>>(score, gmean, row, sel, xmask);
  k_ea3<<<gr(E_ * CE_, 256), 256, 0, stream>>>(A, score);

  // ---- connected components (fused; block-local per graph) ----
  k_cc<<<B_, 256, 0, stream>>>(rp, row, col, sel, lab);
  k_isrep<<<gr(N_, 256), 256, 0, stream>>>(lab, cum);
  k_scan1<<<NB_N, SCAN_B, 0, stream>>>(cum, parts, N_);
  k_scan2<<<1, SCAN_B, 0, stream>>>(parts, NB_N);
  k_scan3<<<NB_N, SCAN_B, 0, stream>>>(cum, parts, N_);
  k_crep<<<1, 128, 0, stream>>>(cum, crep);
  k_comp<<<gr(N_, 256), 256, 0, stream>>>(cum, lab, comp);
  k_cnt<<<gr(N_, 256), 256, 0, stream>>>(comp, batch, xmask, cnt, bsum, keep);
  k_batchout<<<gr(N_, 256), 256, 0, stream>>>(cnt, bsum, bout);

  // ---- EGIN conv ----
  k_agg<<<N_, 128, 0, stream>>>(x, A, col, rp, sel, W_edge, epsp, hc);
  k_gemm128<true><<<N_ / 16, 256, 0, stream>>>(hc, W1, b1, h1);
  k_gemm128<false><<<N_ / 16, 256, 0, stream>>>(h1, W2, b2, hc);  // hc = x_conv

  // ---- pooling (bitmask gather, fused pool+select) ----
  k_nbits<<<gr(N_, 256), 256, 0, stream>>>(comp, nbits);
  k_pool_g<<<gr(N_ * CX_, 256), 256, 0, stream>>>(hc, x, nbits, cnt, bsum, xmask, keep, xout);

  // ---- edge coalesce: presence bits -> rank -> counting-sort gather ----
  k_presbits<<<gr(E_, 256), 256, 0, stream>>>(row, col, sel, comp, crep, bits);
  k_dcount<<<gr(N_, 256), 256, 0, stream>>>(bits, dscan);
  k_scan1<<<NB_N, SCAN_B, 0, stream>>>(dscan, parts, N_);
  k_scan2<<<1, SCAN_B, 0, stream>>>(parts, NB_N);
  k_scan3<<<NB_N, SCAN_B, 0, stream>>>(dscan, parts, N_);
  k_grank<<<gr(E_, 256), 256, 0, stream>>>(row, col, sel, comp, crep, bits, dscan, pos);
  k_gcount<<<gr(E_, 256), 256, 0, stream>>>(pos, gcnt, rloc);
  k_scan1<<<NB_E, SCAN_B, 0, stream>>>(gcnt, parts, E_);
  k_scan2<<<1, SCAN_B, 0, stream>>>(parts, NB_E);
  k_scan3<<<NB_E, SCAN_B, 0, stream>>>(gcnt, parts, E_);
  k_gscatter<<<gr(E_, 256), 256, 0, stream>>>(pos, gcnt, rloc, eord);
  k_attr_g<<<gr(E_ * CE_, 256), 256, 0, stream>>>(A, gcnt, eord, dscan, attr_out);
  k_eidx<<<gr(N_, 256), 256, 0, stream>>>(bits, dscan, cnt, bsum, crep, ei0, ei1);

  // ---- global pool + BN ----
  k_xg<<<B_, CX_, 0, stream>>>(xout, crep, xg_raw);
  k_xgbn<<<1, CX_, 0, stream>>>(xg_raw, bn_g, bn_b, xg);
}

// Round 4
// 1430.714 us; speedup vs baseline: 3.4870x; 3.4870x over previous
//
#include <hip/hip_runtime.h>
#include <cstdint>
#include <cstddef>

#define N_ 46080
#define B_ 64
#define BLKG 720
#define E_ 400000
#define CX_ 128
#define CE_ 32
#define BNEPS_ 1e-5f
#define CC_ITERS_ 40
#define BITW 24   // words of presence bitmask (768 bits >= 720)
#define SCAN_B 1024
#define CCCAP 7424

static inline int gr(int n, int b) { return (n + b - 1) / b; }

// ---------------- CSR / reverse-edge ----------------

__global__ void k_rowptr(const int* __restrict__ row, int* __restrict__ rp) {
  int n = blockIdx.x * blockDim.x + threadIdx.x;
  if (n > N_) return;
  int lo = 0, hi = E_;
  while (lo < hi) { int mid = (lo + hi) >> 1; if (row[mid] < n) lo = mid + 1; else hi = mid; }
  rp[n] = lo;
}

__global__ void k_pos(const int* __restrict__ row, const int* __restrict__ col,
                      int* __restrict__ pos) {
  int e = blockIdx.x * blockDim.x + threadIdx.x;
  if (e >= E_) return;
  long long target = (long long)col[e] * N_ + row[e];
  int lo = 0, hi = E_ - 1;
  while (lo < hi) {
    int mid = (lo + hi) >> 1;
    long long k = (long long)row[mid] * N_ + col[mid];
    if (k < target) lo = mid + 1; else hi = mid;
  }
  pos[e] = lo;
}

__global__ void k_tgt(const float* __restrict__ attr, const int* __restrict__ pos,
                      const int* __restrict__ rp, float* __restrict__ tgt) {
  int t = blockIdx.x * blockDim.x + threadIdx.x;
  if (t >= N_ * CE_) return;
  int n = t / CE_, k = t % CE_;
  float s = 0.f;
  int b = rp[n], e = rp[n + 1];
  for (int i = b; i < e; i++) s += attr[(size_t)pos[i] * CE_ + k];
  tgt[t] = s;
}

// ---------------- fused edge_prop + Linear(32->32) ----------------
// sA = tgt[row[e]] + attr[e]  (identical adds to the old k_eaprop), then GEMM.

__global__ void k_mlp2(const float* __restrict__ attr, const float* __restrict__ tgt,
                       const int* __restrict__ row, const float* __restrict__ We,
                       const float* __restrict__ be, float* __restrict__ H) {
  __shared__ float sWe[CE_ * CE_];
  __shared__ float sA[8 * CE_];
  int t = threadIdx.x;
  for (int i = t; i < CE_ * CE_; i += 256) sWe[i] = We[i];
  int e0 = blockIdx.x * 8;
  for (int i = t; i < 8 * CE_; i += 256) {
    int el = i >> 5, ki = i & 31;
    int e = e0 + el;
    sA[i] = tgt[(size_t)row[e] * CE_ + ki] + attr[(size_t)e * CE_ + ki];
  }
  __syncthreads();
  int el = t >> 5, j = t & 31;
  float acc = be[j];
  for (int k = 0; k < CE_; k++) acc += sA[el * CE_ + k] * sWe[k * CE_ + j];
  H[(size_t)(e0 + el) * CE_ + j] = acc;
}

__global__ void k_bnstats(const float* __restrict__ H, double* __restrict__ acc) {
  int t = threadIdx.x; int ch = t & 31, grp = t >> 5;
  double s = 0.0, s2 = 0.0;
  for (int e = blockIdx.x * 8 + grp; e < E_; e += gridDim.x * 8) {
    double v = H[(size_t)e * CE_ + ch];
    s += v; s2 += v * v;
  }
  __shared__ double sh[256], sh2[256];
  sh[t] = s; sh2[t] = s2; __syncthreads();
  for (int off = 128; off >= 32; off >>= 1) {
    if (t < off) { sh[t] += sh[t + off]; sh2[t] += sh2[t + off]; }
    __syncthreads();
  }
  if (t < 32) { atomicAdd(&acc[ch], sh[t]); atomicAdd(&acc[32 + ch], sh2[t]); }
}

__global__ void k_bnfin(const double* __restrict__ acc, const float* __restrict__ g,
                        const float* __restrict__ b, const float* __restrict__ S,
                        float* __restrict__ scale, float* __restrict__ shift,
                        float* __restrict__ snorm) {
  int t = threadIdx.x;
  if (t < CE_) {
    double mu = acc[t] / (double)E_;
    double var = acc[32 + t] / (double)E_ - mu * mu;
    float sc = (float)((double)g[t] / sqrt(var + 1e-5));
    scale[t] = sc;
    shift[t] = b[t] - (float)mu * sc;
  }
  if (t == 0) {
    float s = 0.f;
    for (int k = 0; k < CE_; k++) s += S[k] * S[k];
    *snorm = sqrtf(s);
  }
}

// ---------------- fused BN-apply + ReLU + S-dot (q-order identical to old k_tdot) ----

__global__ void k_bnT(const float* __restrict__ H, const float* __restrict__ scale,
                      const float* __restrict__ shift, const float* __restrict__ S,
                      float* __restrict__ A, float* __restrict__ tdot) {
  __shared__ float ssc[CE_], ssh[CE_], sS[CE_];
  if (threadIdx.x < CE_) {
    ssc[threadIdx.x] = scale[threadIdx.x];
    ssh[threadIdx.x] = shift[threadIdx.x];
    sS[threadIdx.x] = S[threadIdx.x];
  }
  __syncthreads();
  int e = blockIdx.x * blockDim.x + threadIdx.x;
  if (e >= E_) return;
  const float4* h4 = (const float4*)(H + (size_t)e * CE_);
  float4* a4 = (float4*)(A + (size_t)e * CE_);
  float s = 0.f;
  for (int q = 0; q < 8; q++) {
    float4 v = h4[q];
    float4 r;
    r.x = fmaxf(v.x * ssc[q * 4 + 0] + ssh[q * 4 + 0], 0.f);
    r.y = fmaxf(v.y * ssc[q * 4 + 1] + ssh[q * 4 + 1], 0.f);
    r.z = fmaxf(v.z * ssc[q * 4 + 2] + ssh[q * 4 + 2], 0.f);
    r.w = fmaxf(v.w * ssc[q * 4 + 3] + ssh[q * 4 + 3], 0.f);
    a4[q] = r;
    s += r.x * sS[q * 4 + 0] + r.y * sS[q * 4 + 1] + r.z * sS[q * 4 + 2] + r.w * sS[q * 4 + 3];
  }
  tdot[e] = s;
}

__global__ void k_score(const float* __restrict__ tdot, const int* __restrict__ pos,
                        const float* __restrict__ snorm, float* __restrict__ score) {
  int e = blockIdx.x * blockDim.x + threadIdx.x;
  if (e >= E_) return;
  float z = (tdot[e] + tdot[pos[e]]) / (*snorm);
  score[e] = 1.f / (1.f + expf(-z));
}

__global__ void k_gmean(const float* __restrict__ score, const int* __restrict__ rp,
                        float* __restrict__ gmean) {
  int g = blockIdx.x; int t = threadIdx.x;
  int b = rp[g * BLKG], e = rp[(g + 1) * BLKG];
  float s = 0.f;
  for (int i = b + t; i < e; i += 256) s += score[i];
  __shared__ float sh[256];
  sh[t] = s; __syncthreads();
  for (int off = 128; off; off >>= 1) { if (t < off) sh[t] += sh[t + off]; __syncthreads(); }
  if (t == 0) gmean[g] = sh[0] / (float)(e - b);
}

__global__ void k_sel(const float* __restrict__ score, const float* __restrict__ gmean,
                      const int* __restrict__ row,
                      int* __restrict__ sel, int* __restrict__ xmask) {
  int e = blockIdx.x * blockDim.x + threadIdx.x;
  if (e >= E_) return;
  int r = row[e];
  int g = r / BLKG;
  float s = score[e];
  int v = (s <= 0.5f) && (s < gmean[g]);
  sel[e] = v;
  if (v) atomicOr(&xmask[r], 1);
}

// ---------------- connected components: fused, LDS-resident edge list ----------------

__global__ __launch_bounds__(256) void k_cc(const int* __restrict__ rp,
                                            const int* __restrict__ row,
                                            const int* __restrict__ col,
                                            const int* __restrict__ sel,
                                            int* __restrict__ lab_g) {
  __shared__ int lab[BLKG], cur[BLKG];
  __shared__ unsigned int rc[CCCAP];
  __shared__ int nsel_s, novf;
  int g = blockIdx.x, t = threadIdx.x;
  int base = g * BLKG;
  int e0 = rp[base], e1 = rp[base + BLKG];
  if (t == 0) { nsel_s = 0; novf = 0; }
  for (int i = t; i < BLKG; i += 256) lab[i] = i;
  __syncthreads();
  for (int e = e0 + t; e < e1; e += 256) {
    if (sel[e]) {
      int i = atomicAdd(&nsel_s, 1);
      if (i < CCCAP) rc[i] = ((unsigned)(row[e] - base) << 16) | (unsigned)(col[e] - base);
      else novf = 1;
    }
  }
  __syncthreads();
  int ns = nsel_s < CCCAP ? nsel_s : CCCAP;
  int ovf = novf;
  for (int it = 0; it < CC_ITERS_; ++it) {
    for (int i = t; i < BLKG; i += 256) cur[i] = lab[i];
    __syncthreads();
    for (int i = t; i < ns; i += 256) {
      unsigned v = rc[i]; int r = v >> 16, c = v & 0xffff;
      atomicMin(&cur[r], lab[c]);
      atomicMin(&cur[c], lab[r]);
    }
    if (ovf) {  // idempotent for min: re-process all selected edges from global
      for (int e = e0 + t; e < e1; e += 256) {
        if (sel[e]) {
          int r = row[e] - base, c = col[e] - base;
          atomicMin(&cur[r], lab[c]);
          atomicMin(&cur[c], lab[r]);
        }
      }
    }
    __syncthreads();
    for (int i = t; i < BLKG; i += 256) {
      int v = cur[i]; v = cur[v]; v = cur[v]; v = cur[v];  // m=m[m]; m=m[m]
      lab[i] = v;
    }
    __syncthreads();
  }
  for (int i = t; i < BLKG; i += 256) lab_g[base + i] = base + lab[i];
}

__global__ void k_isrep(const int* __restrict__ lab, int* __restrict__ cum) {
  int n = blockIdx.x * blockDim.x + threadIdx.x;
  if (n < N_) cum[n] = (lab[n] == n) ? 1 : 0;
}

// ---------------- multi-block inclusive scan ----------------

__global__ void k_scan1(int* __restrict__ d, int* __restrict__ parts, int n) {
  __shared__ int s[SCAN_B];
  int i = blockIdx.x * SCAN_B + threadIdx.x;
  int v = (i < n) ? d[i] : 0;
  s[threadIdx.x] = v; __syncthreads();
  for (int off = 1; off < SCAN_B; off <<= 1) {
    int t2 = (threadIdx.x >= off) ? s[threadIdx.x - off] : 0;
    __syncthreads();
    s[threadIdx.x] += t2;
    __syncthreads();
  }
  if (i < n) d[i] = s[threadIdx.x];
  if (threadIdx.x == SCAN_B - 1) parts[blockIdx.x] = s[SCAN_B - 1];
}

__global__ void k_scan2(int* __restrict__ parts, int nb) {
  __shared__ int s[SCAN_B];
  int v = ((int)threadIdx.x < nb) ? parts[threadIdx.x] : 0;
  s[threadIdx.x] = v; __syncthreads();
  for (int off = 1; off < SCAN_B; off <<= 1) {
    int t2 = (threadIdx.x >= off) ? s[threadIdx.x - off] : 0;
    __syncthreads();
    s[threadIdx.x] += t2;
    __syncthreads();
  }
  if ((int)threadIdx.x < nb) parts[threadIdx.x] = s[threadIdx.x];
}

__global__ void k_scan3(int* __restrict__ d, const int* __restrict__ parts, int n) {
  int i = blockIdx.x * SCAN_B + threadIdx.x;
  if (i < n && blockIdx.x > 0) d[i] += parts[blockIdx.x - 1];
}

// ---------------- comp / counts ----------------

__global__ void k_crep(const int* __restrict__ cum, int* __restrict__ crep) {
  int g = threadIdx.x;
  if (g <= B_) crep[g] = (g == 0) ? 0 : cum[g * BLKG - 1];
}

__global__ void k_comp(const int* __restrict__ cum, const int* __restrict__ lab,
                       int* __restrict__ comp) {
  int n = blockIdx.x * blockDim.x + threadIdx.x;
  if (n < N_) comp[n] = cum[lab[n]] - 1;
}

__global__ void k_cnt(const int* __restrict__ comp, const int* __restrict__ batch,
                      const int* __restrict__ xmask, int* __restrict__ cnt,
                      int* __restrict__ bsum, int* __restrict__ keep) {
  int n = blockIdx.x * blockDim.x + threadIdx.x;
  if (n >= N_) return;
  int c = comp[n];
  atomicAdd(&cnt[c], 1);
  atomicAdd(&bsum[c], batch[n]);
  if (!xmask[n]) atomicAdd(&keep[c], 1);
}

__global__ void k_batchout(const int* __restrict__ cnt, const int* __restrict__ bsum,
                           float* __restrict__ bout) {
  int c = blockIdx.x * blockDim.x + threadIdx.x;
  if (c >= N_) return;
  int ct = cnt[c];
  bout[c] = (float)(bsum[c] / (ct > 0 ? ct : 1));
}

// ---------------- EGIN conv (score folded in: sea = A*score) ----------------

__global__ void k_agg(const float* __restrict__ x, const float* __restrict__ A,
                      const float* __restrict__ score,
                      const int* __restrict__ col, const int* __restrict__ rp,
                      const int* __restrict__ sel, const float* __restrict__ W_edge,
                      const float* __restrict__ epsp, float* __restrict__ hc) {
  __shared__ float sW[CE_ * CX_];
  __shared__ float sea[CE_];
  int n = blockIdx.x, t = threadIdx.x;  // 128 threads
  for (int i = t; i < CE_ * CX_; i += 128) sW[i] = W_edge[i];
  float acc = 0.f;
  int b = rp[n], e = rp[n + 1];
  for (int i = b; i < e; i++) {
    if (!sel[i]) continue;
    __syncthreads();
    if (t < CE_) sea[t] = A[(size_t)i * CE_ + t] * score[i];
    __syncthreads();
    float m = x[(size_t)col[i] * CX_ + t];
    for (int k = 0; k < CE_; k++) m += sea[k] * sW[k * CX_ + t];
    acc += fmaxf(m, 0.f);
  }
  hc[(size_t)n * CX_ + t] = (1.f + epsp[0]) * x[(size_t)n * CX_ + t] + acc;
}

template <bool RELU>
__global__ void k_gemm128(const float* __restrict__ X, const float* __restrict__ W,
                          const float* __restrict__ bias, float* __restrict__ Y) {
  __shared__ float sX[16 * CX_];
  int t = threadIdx.x;
  int r0 = blockIdx.x * 16;
  for (int i = t; i < 16 * CX_; i += 256) sX[i] = X[(size_t)r0 * CX_ + i];
  __syncthreads();
  int j = t & 127, rl = t >> 7;
  float acc[8];
  for (int i = 0; i < 8; i++) acc[i] = 0.f;
  for (int k = 0; k < CX_; k++) {
    float w = W[k * CX_ + j];
    for (int i = 0; i < 8; i++) acc[i] += sX[(rl + 2 * i) * CX_ + k] * w;
  }
  float b = bias[j];
  for (int i = 0; i < 8; i++) {
    float v = acc[i] + b;
    if (RELU) v = fmaxf(v, 0.f);
    Y[(size_t)(r0 + rl + 2 * i) * CX_ + j] = v;
  }
}

// ---------------- pooling: block per cluster, node list in LDS ----------------

__global__ void k_nbits(const int* __restrict__ comp, unsigned int* __restrict__ nbits) {
  int n = blockIdx.x * blockDim.x + threadIdx.x;
  if (n >= N_) return;
  int c = comp[n];
  int j = n % BLKG;
  atomicOr(&nbits[(size_t)c * BITW + (j >> 5)], 1u << (j & 31));
}

__global__ __launch_bounds__(512) void k_pool2(const float* __restrict__ xc,
                                               const float* __restrict__ x,
                                               const unsigned int* __restrict__ nbits,
                                               const int* __restrict__ cnt,
                                               const int* __restrict__ bsum,
                                               const int* __restrict__ xmask,
                                               const int* __restrict__ keep,
                                               float* __restrict__ xout) {
  __shared__ int nodes[BLKG];
  __shared__ int nn;
  __shared__ float part[4 * CX_];
  int c = blockIdx.x, t = threadIdx.x;
  int ct = cnt[c];
  if (ct == 0) { if (t < CX_) xout[(size_t)c * CX_ + t] = 0.f; return; }
  if (t == 0) {
    int g = bsum[c] / ct; int base = g * BLKG; int m = 0;
    for (int w = 0; w < BITW; w++) {
      unsigned int word = nbits[(size_t)c * BITW + w];
      while (word) { int j = __ffs(word) - 1; word &= word - 1; nodes[m++] = base + w * 32 + j; }
    }
    nn = m;
  }
  __syncthreads();
  int ch = t & 127, sub = t >> 7;
  int kp = keep[c];
  float s = 0.f;
  int m = nn;
  for (int i = sub; i < m; i += 4) {
    int n = nodes[i];
    int xm = xmask[n];
    if (kp > 0) { if (!xm) s += x[(size_t)n * CX_ + ch]; }
    else        { if (xm)  s += xc[(size_t)n * CX_ + ch]; }
  }
  part[t] = s; __syncthreads();
  if (t < 256) part[t] += part[t + 256];
  __syncthreads();
  if (t < 128) xout[(size_t)c * CX_ + t] = part[t] + part[t + 128];
}

// ---------------- edge coalesce (presence bits -> rank -> run-compressed add) ----

__global__ void k_fillm1(float* __restrict__ p, int n) {
  int t = blockIdx.x * blockDim.x + threadIdx.x;
  if (t < n) p[t] = -1.0f;
}

__global__ void k_presbits(const int* __restrict__ row, const int* __restrict__ col,
                           const int* __restrict__ sel, const int* __restrict__ comp,
                           const int* __restrict__ crep, unsigned int* __restrict__ bits) {
  int e = blockIdx.x * blockDim.x + threadIdx.x;
  if (e >= E_ || sel[e]) return;
  int cu = comp[row[e]], cv = comp[col[e]];
  int g = row[e] / BLKG;
  int j = cv - crep[g];
  atomicOr(&bits[(size_t)cu * BITW + (j >> 5)], 1u << (j & 31));
}

__global__ void k_dcount(const unsigned int* __restrict__ bits, int* __restrict__ dscan) {
  int cu = blockIdx.x * blockDim.x + threadIdx.x;
  if (cu >= N_) return;
  int s = 0;
  for (int w = 0; w < BITW; w++) s += __popc(bits[(size_t)cu * BITW + w]);
  dscan[cu] = s;
}

__global__ void k_grank(const int* __restrict__ row, const int* __restrict__ col,
                        const int* __restrict__ sel, const int* __restrict__ comp,
                        const int* __restrict__ crep, const unsigned int* __restrict__ bits,
                        const int* __restrict__ dscan, int* __restrict__ grank) {
  int e = blockIdx.x * blockDim.x + threadIdx.x;
  if (e >= E_) return;
  if (sel[e]) { grank[e] = -1; return; }
  int cu = comp[row[e]], cv = comp[col[e]];
  int g = row[e] / BLKG;
  int j = cv - crep[g];
  int base = (cu > 0) ? dscan[cu - 1] : 0;
  int r = 0, wj = j >> 5;
  for (int w = 0; w < wj; w++) r += __popc(bits[(size_t)cu * BITW + w]);
  unsigned int mask = (1u << (j & 31)) - 1u;
  r += __popc(bits[(size_t)cu * BITW + wj] & mask);
  grank[e] = base + r;
}

// run-compressed accumulation: lane = channel, thread walks 32 consecutive edges.
// Long grank runs (giant clusters) -> few atomics; parallel over all edges.
__global__ void k_attr_r(const float* __restrict__ A, const float* __restrict__ score,
                         const int* __restrict__ grank, float* __restrict__ attr_out) {
  int t = blockIdx.x * blockDim.x + threadIdx.x;
  if (t >= E_) return;
  int w = t >> 5, k = t & 31;
  int e0 = w * 32, e1 = e0 + 32;
  if (e1 > E_) e1 = E_;
  float acc = 0.f; int cs = -1;
  for (int e = e0; e < e1; ++e) {
    int s = grank[e];
    if (s < 0) continue;
    float v = A[(size_t)e * CE_ + k] * score[e];
    if (s != cs) {
      if (cs >= 0) atomicAdd(&attr_out[(size_t)cs * CE_ + k], acc);
      cs = s; acc = v;
    } else acc += v;
  }
  if (cs >= 0) atomicAdd(&attr_out[(size_t)cs * CE_ + k], acc);
}

__global__ void k_eidx(const unsigned int* __restrict__ bits, const int* __restrict__ dscan,
                       const int* __restrict__ cnt, const int* __restrict__ bsum,
                       const int* __restrict__ crep, float* __restrict__ ei0,
                       float* __restrict__ ei1) {
  int cu = blockIdx.x * blockDim.x + threadIdx.x;
  if (cu >= N_) return;
  int base = (cu > 0) ? dscan[cu - 1] : 0;
  int ct = cnt[cu];
  int g = bsum[cu] / (ct > 0 ? ct : 1);
  int cb = crep[g];
  int r = 0;
  for (int w = 0; w < BITW; w++) {
    unsigned int word = bits[(size_t)cu * BITW + w];
    while (word) {
      int bitj = __ffs(word) - 1;
      int j = w * 32 + bitj;
      ei0[base + r] = (float)cu;
      ei1[base + r] = (float)(cb + j);
      r++;
      word &= word - 1;
    }
  }
}

// ---------------- global pool + BN ----------------

__global__ void k_xg(const float* __restrict__ xout, const int* __restrict__ crep,
                     float* __restrict__ xg_raw) {
  int b = blockIdx.x, ch = threadIdx.x;
  float s = 0.f;
  int c0 = crep[b], c1 = crep[b + 1];
  for (int c = c0; c < c1; c++) s += xout[(size_t)c * CX_ + ch];
  xg_raw[b * CX_ + ch] = s;
}

__global__ void k_xgbn(const float* __restrict__ xg_raw, const float* __restrict__ g,
                       const float* __restrict__ bb, float* __restrict__ xg) {
  int ch = threadIdx.x;
  float mu = 0.f;
  for (int b = 0; b < B_; b++) mu += xg_raw[b * CX_ + ch];
  mu /= (float)B_;
  float var = 0.f;
  for (int b = 0; b < B_; b++) { float d = xg_raw[b * CX_ + ch] - mu; var += d * d; }
  var /= (float)B_;
  float sc = g[ch] / sqrtf(var + BNEPS_);
  for (int b = 0; b < B_; b++)
    xg[b * CX_ + ch] = (xg_raw[b * CX_ + ch] - mu) * sc + bb[ch];
}

// ---------------- launch ----------------

extern "C" void kernel_launch(void* const* d_in, const int* in_sizes, int n_in,
                              void* d_out, int out_size, void* d_ws, size_t ws_size,
                              hipStream_t stream) {
  const float* x      = (const float*)d_in[0];
  const int*   ei     = (const int*)d_in[1];
  const int*   row    = ei;
  const int*   col    = ei + E_;
  const float* eattr  = (const float*)d_in[2];
  const int*   batch  = (const int*)d_in[3];
  const float* S      = (const float*)d_in[4];
  const float* We     = (const float*)d_in[5];
  const float* be     = (const float*)d_in[6];
  const float* bn_e_g = (const float*)d_in[7];
  const float* bn_e_b = (const float*)d_in[8];
  const float* W_edge = (const float*)d_in[9];
  const float* epsp   = (const float*)d_in[10];
  const float* W1     = (const float*)d_in[11];
  const float* b1     = (const float*)d_in[12];
  const float* W2     = (const float*)d_in[13];
  const float* b2     = (const float*)d_in[14];
  const float* bn_g   = (const float*)d_in[15];
  const float* bn_b   = (const float*)d_in[16];

  float* xout     = (float*)d_out;
  float* ei0      = (float*)d_out + (size_t)N_ * CX_;
  float* ei1      = ei0 + E_;
  float* attr_out = (float*)d_out + (size_t)N_ * CX_ + 2 * (size_t)E_;
  float* bout     = (float*)d_out + (size_t)N_ * CX_ + 2 * (size_t)E_ + (size_t)E_ * CE_;
  float* xg       = (float*)d_out + (size_t)N_ * CX_ + 2 * (size_t)E_ + (size_t)E_ * CE_ + N_;

  char* w = (char*)d_ws;
  size_t off = 0;
  auto alloc = [&](size_t bytes) -> void* {
    void* p = w + off;
    off += (bytes + 511) & ~(size_t)511;
    return p;
  };
  double* bnacc = (double*)alloc(64 * 8);
  float* A      = (float*)alloc((size_t)E_ * CE_ * 4);   // post-BN ea
  float* Hb     = (float*)alloc((size_t)E_ * CE_ * 4);   // pre-BN linear out
  float* tgt    = (float*)alloc((size_t)N_ * CE_ * 4);
  float* hc     = (float*)alloc((size_t)N_ * CX_ * 4);
  float* h1     = (float*)alloc((size_t)N_ * CX_ * 4);
  int*   pos    = (int*)alloc((size_t)E_ * 4);   // later reused as grank
  float* tdot   = (float*)alloc((size_t)E_ * 4);
  float* score  = (float*)alloc((size_t)E_ * 4);
  int*   sel    = (int*)alloc((size_t)E_ * 4);
  int*   rp     = (int*)alloc((size_t)(N_ + 1) * 4);
  int*   cum    = (int*)alloc((size_t)N_ * 4);
  int*   comp   = (int*)alloc((size_t)N_ * 4);
  int*   lab    = (int*)alloc((size_t)N_ * 4);
  int*   cnt    = (int*)alloc((size_t)N_ * 4);
  int*   bsum   = (int*)alloc((size_t)N_ * 4);
  int*   keep   = (int*)alloc((size_t)N_ * 4);
  int*   xmask  = (int*)alloc((size_t)N_ * 4);
  int*   dscan  = (int*)alloc((size_t)N_ * 4);
  unsigned int* bits  = (unsigned int*)alloc((size_t)N_ * BITW * 4);
  unsigned int* nbits = (unsigned int*)alloc((size_t)N_ * BITW * 4);
  int*   parts  = (int*)alloc(1024 * 4);
  int*   crep   = (int*)alloc((size_t)(B_ + 1) * 4);
  float* gmean  = (float*)alloc((size_t)B_ * 4);
  float* xg_raw = (float*)alloc((size_t)B_ * CX_ * 4);
  float* scale  = (float*)alloc(CE_ * 4);
  float* shift  = (float*)alloc(CE_ * 4);
  float* snorm  = (float*)alloc(4);
  if (off > ws_size) return;

  const int NB_N = gr(N_, SCAN_B);   // 45

  // ---- zero/init ----
  hipMemsetAsync(bnacc, 0, 64 * 8, stream);
  hipMemsetAsync(cnt, 0, (size_t)N_ * 4, stream);
  hipMemsetAsync(bsum, 0, (size_t)N_ * 4, stream);
  hipMemsetAsync(keep, 0, (size_t)N_ * 4, stream);
  hipMemsetAsync(xmask, 0, (size_t)N_ * 4, stream);
  hipMemsetAsync(bits, 0, (size_t)N_ * BITW * 4, stream);
  hipMemsetAsync(nbits, 0, (size_t)N_ * BITW * 4, stream);
  hipMemsetAsync(attr_out, 0, (size_t)E_ * CE_ * 4, stream);
  k_fillm1<<<gr(2 * E_, 256), 256, 0, stream>>>(ei0, 2 * E_);

  // ---- edge prop + mlp_e (fused) ----
  k_rowptr<<<gr(N_ + 1, 256), 256, 0, stream>>>(row, rp);
  k_pos<<<gr(E_, 256), 256, 0, stream>>>(row, col, pos);
  k_tgt<<<gr(N_ * CE_, 256), 256, 0, stream>>>(eattr, pos, rp, tgt);
  k_mlp2<<<E_ / 8, 256, 0, stream>>>(eattr, tgt, row, We, be, Hb);
  k_bnstats<<<512, 256, 0, stream>>>(Hb, bnacc);
  k_bnfin<<<1, 64, 0, stream>>>(bnacc, bn_e_g, bn_e_b, S, scale, shift, snorm);
  k_bnT<<<gr(E_, 256), 256, 0, stream>>>(Hb, scale, shift, S, A, tdot);

  // ---- score / selection (numeric path unchanged) ----
  k_score<<<gr(E_, 256), 256, 0, stream>>>(tdot, pos, snorm, score);
  k_gmean<<<B_, 256, 0, stream>>>(score, rp, gmean);
  k_sel<<<gr(E_, 256), 256, 0, stream>>>(score, gmean, row, sel, xmask);

  // ---- connected components (LDS-resident) ----
  k_cc<<<B_, 256, 0, stream>>>(rp, row, col, sel, lab);
  k_isrep<<<gr(N_, 256), 256, 0, stream>>>(lab, cum);
  k_scan1<<<NB_N, SCAN_B, 0, stream>>>(cum, parts, N_);
  k_scan2<<<1, SCAN_B, 0, stream>>>(parts, NB_N);
  k_scan3<<<NB_N, SCAN_B, 0, stream>>>(cum, parts, N_);
  k_crep<<<1, 128, 0, stream>>>(cum, crep);
  k_comp<<<gr(N_, 256), 256, 0, stream>>>(cum, lab, comp);
  k_cnt<<<gr(N_, 256), 256, 0, stream>>>(comp, batch, xmask, cnt, bsum, keep);
  k_batchout<<<gr(N_, 256), 256, 0, stream>>>(cnt, bsum, bout);

  // ---- EGIN conv ----
  k_agg<<<N_, 128, 0, stream>>>(x, A, score, col, rp, sel, W_edge, epsp, hc);
  k_gemm128<true><<<N_ / 16, 256, 0, stream>>>(hc, W1, b1, h1);
  k_gemm128<false><<<N_ / 16, 256, 0, stream>>>(h1, W2, b2, hc);  // hc = x_conv

  // ---- pooling ----
  k_nbits<<<gr(N_, 256), 256, 0, stream>>>(comp, nbits);
  k_pool2<<<N_, 512, 0, stream>>>(hc, x, nbits, cnt, bsum, xmask, keep, xout);

  // ---- edge coalesce ----
  k_presbits<<<gr(E_, 256), 256, 0, stream>>>(row, col, sel, comp, crep, bits);
  k_dcount<<<gr(N_, 256), 256, 0, stream>>>(bits, dscan);
  k_scan1<<<NB_N, SCAN_B, 0, stream>>>(dscan, parts, N_);
  k_scan2<<<1, SCAN_B, 0, stream>>>(parts, NB_N);
  k_scan3<<<NB_N, SCAN_B, 0, stream>>>(dscan, parts, N_);
  k_grank<<<gr(E_, 256), 256, 0, stream>>>(row, col, sel, comp, crep, bits, dscan, pos);
  k_attr_r<<<gr(E_, 256), 256, 0, stream>>>(A, score, pos, attr_out);
  k_eidx<<<gr(N_, 256), 256, 0, stream>>>(bits, dscan, cnt, bsum, crep, ei0, ei1);

  // ---- global pool + BN ----
  k_xg<<<B_, CX_, 0, stream>>>(xout, crep, xg_raw);
  k_xgbn<<<1, CX_, 0, stream>>>(xg_raw, bn_g, bn_b, xg);
}

// Round 6
// 1220.428 us; speedup vs baseline: 4.0879x; 1.1723x over previous
//
#include <hip/hip_runtime.h>
#include <cstdint>
#include <cstddef>

#define N_ 46080
#define B_ 64
#define BLKG 720
#define E_ 400000
#define CX_ 128
#define CE_ 32
#define BNEPS_ 1e-5f
#define CC_ITERS_ 40
#define BITW 24   // words of presence bitmask (768 bits >= 720)
#define SCAN_B 1024
#define CCCAP 7424

static inline int gr(int n, int b) { return (n + b - 1) / b; }

// ---------------- CSR / reverse-edge ----------------

__global__ void k_rowptr(const int* __restrict__ row, int* __restrict__ rp) {
  int n = blockIdx.x * blockDim.x + threadIdx.x;
  if (n > N_) return;
  int lo = 0, hi = E_;
  while (lo < hi) { int mid = (lo + hi) >> 1; if (row[mid] < n) lo = mid + 1; else hi = mid; }
  rp[n] = lo;
}

__global__ void k_pos(const int* __restrict__ row, const int* __restrict__ col,
                      int* __restrict__ pos) {
  int e = blockIdx.x * blockDim.x + threadIdx.x;
  if (e >= E_) return;
  long long target = (long long)col[e] * N_ + row[e];
  int lo = 0, hi = E_ - 1;
  while (lo < hi) {
    int mid = (lo + hi) >> 1;
    long long k = (long long)row[mid] * N_ + col[mid];
    if (k < target) lo = mid + 1; else hi = mid;
  }
  pos[e] = lo;
}

__global__ void k_tgt(const float* __restrict__ attr, const int* __restrict__ pos,
                      const int* __restrict__ rp, float* __restrict__ tgt) {
  int t = blockIdx.x * blockDim.x + threadIdx.x;
  if (t >= N_ * CE_) return;
  int n = t / CE_, k = t % CE_;
  float s = 0.f;
  int b = rp[n], e = rp[n + 1];
  for (int i = b; i < e; i++) s += attr[(size_t)pos[i] * CE_ + k];
  tgt[t] = s;
}

// ---------------- fused edge_prop + Linear(32->32) ----------------

__global__ void k_mlp2(const float* __restrict__ attr, const float* __restrict__ tgt,
                       const int* __restrict__ row, const float* __restrict__ We,
                       const float* __restrict__ be, float* __restrict__ H) {
  __shared__ float sWe[CE_ * CE_];
  __shared__ float sA[8 * CE_];
  int t = threadIdx.x;
  for (int i = t; i < CE_ * CE_; i += 256) sWe[i] = We[i];
  int e0 = blockIdx.x * 8;
  for (int i = t; i < 8 * CE_; i += 256) {
    int el = i >> 5, ki = i & 31;
    int e = e0 + el;
    sA[i] = tgt[(size_t)row[e] * CE_ + ki] + attr[(size_t)e * CE_ + ki];
  }
  __syncthreads();
  int el = t >> 5, j = t & 31;
  float acc = be[j];
  for (int k = 0; k < CE_; k++) acc += sA[el * CE_ + k] * sWe[k * CE_ + j];
  H[(size_t)(e0 + el) * CE_ + j] = acc;
}

__global__ void k_bnstats(const float* __restrict__ H, double* __restrict__ acc) {
  int t = threadIdx.x; int ch = t & 31, grp = t >> 5;
  double s = 0.0, s2 = 0.0;
  for (int e = blockIdx.x * 8 + grp; e < E_; e += gridDim.x * 8) {
    double v = H[(size_t)e * CE_ + ch];
    s += v; s2 += v * v;
  }
  __shared__ double sh[256], sh2[256];
  sh[t] = s; sh2[t] = s2; __syncthreads();
  for (int off = 128; off >= 32; off >>= 1) {
    if (t < off) { sh[t] += sh[t + off]; sh2[t] += sh2[t + off]; }
    __syncthreads();
  }
  if (t < 32) { atomicAdd(&acc[ch], sh[t]); atomicAdd(&acc[32 + ch], sh2[t]); }
}

__global__ void k_bnfin(const double* __restrict__ acc, const float* __restrict__ g,
                        const float* __restrict__ b, const float* __restrict__ S,
                        float* __restrict__ scale, float* __restrict__ shift,
                        float* __restrict__ snorm) {
  int t = threadIdx.x;
  if (t < CE_) {
    double mu = acc[t] / (double)E_;
    double var = acc[32 + t] / (double)E_ - mu * mu;
    float sc = (float)((double)g[t] / sqrt(var + 1e-5));
    scale[t] = sc;
    shift[t] = b[t] - (float)mu * sc;
  }
  if (t == 0) {
    float s = 0.f;
    for (int k = 0; k < CE_; k++) s += S[k] * S[k];
    *snorm = sqrtf(s);
  }
}

// ---------------- fused BN-apply + ReLU + S-dot ----------------

__global__ void k_bnT(const float* __restrict__ H, const float* __restrict__ scale,
                      const float* __restrict__ shift, const float* __restrict__ S,
                      float* __restrict__ A, float* __restrict__ tdot) {
  __shared__ float ssc[CE_], ssh[CE_], sS[CE_];
  if (threadIdx.x < CE_) {
    ssc[threadIdx.x] = scale[threadIdx.x];
    ssh[threadIdx.x] = shift[threadIdx.x];
    sS[threadIdx.x] = S[threadIdx.x];
  }
  __syncthreads();
  int e = blockIdx.x * blockDim.x + threadIdx.x;
  if (e >= E_) return;
  const float4* h4 = (const float4*)(H + (size_t)e * CE_);
  float4* a4 = (float4*)(A + (size_t)e * CE_);
  float s = 0.f;
  for (int q = 0; q < 8; q++) {
    float4 v = h4[q];
    float4 r;
    r.x = fmaxf(v.x * ssc[q * 4 + 0] + ssh[q * 4 + 0], 0.f);
    r.y = fmaxf(v.y * ssc[q * 4 + 1] + ssh[q * 4 + 1], 0.f);
    r.z = fmaxf(v.z * ssc[q * 4 + 2] + ssh[q * 4 + 2], 0.f);
    r.w = fmaxf(v.w * ssc[q * 4 + 3] + ssh[q * 4 + 3], 0.f);
    a4[q] = r;
    s += r.x * sS[q * 4 + 0] + r.y * sS[q * 4 + 1] + r.z * sS[q * 4 + 2] + r.w * sS[q * 4 + 3];
  }
  tdot[e] = s;
}

__global__ void k_score(const float* __restrict__ tdot, const int* __restrict__ pos,
                        const float* __restrict__ snorm, float* __restrict__ score) {
  int e = blockIdx.x * blockDim.x + threadIdx.x;
  if (e >= E_) return;
  float z = (tdot[e] + tdot[pos[e]]) / (*snorm);
  score[e] = 1.f / (1.f + expf(-z));
}

__global__ void k_gmean(const float* __restrict__ score, const int* __restrict__ rp,
                        float* __restrict__ gmean) {
  int g = blockIdx.x; int t = threadIdx.x;
  int b = rp[g * BLKG], e = rp[(g + 1) * BLKG];
  float s = 0.f;
  for (int i = b + t; i < e; i += 256) s += score[i];
  __shared__ float sh[256];
  sh[t] = s; __syncthreads();
  for (int off = 128; off; off >>= 1) { if (t < off) sh[t] += sh[t + off]; __syncthreads(); }
  if (t == 0) gmean[g] = sh[0] / (float)(e - b);
}

__global__ void k_sel(const float* __restrict__ score, const float* __restrict__ gmean,
                      const int* __restrict__ row,
                      int* __restrict__ sel, int* __restrict__ xmask) {
  int e = blockIdx.x * blockDim.x + threadIdx.x;
  if (e >= E_) return;
  int r = row[e];
  int g = r / BLKG;
  float s = score[e];
  int v = (s <= 0.5f) && (s < gmean[g]);
  sel[e] = v;
  if (v) atomicOr(&xmask[r], 1);
}

// ---------------- connected components: LDS, early-exit on convergence -------
// body() is idempotent at its fixed point (labels == component min), so
// stopping when no label changes is bit-exact vs the reference's 40 iters.

__global__ __launch_bounds__(256) void k_cc(const int* __restrict__ rp,
                                            const int* __restrict__ row,
                                            const int* __restrict__ col,
                                            const int* __restrict__ sel,
                                            int* __restrict__ lab_g,
                                            int* __restrict__ cum) {
  __shared__ int lab[BLKG], cur[BLKG];
  __shared__ unsigned int rc[CCCAP];
  __shared__ int nsel_s, novf, chg;
  int g = blockIdx.x, t = threadIdx.x;
  int base = g * BLKG;
  int e0 = rp[base], e1 = rp[base + BLKG];
  if (t == 0) { nsel_s = 0; novf = 0; }
  for (int i = t; i < BLKG; i += 256) lab[i] = i;
  __syncthreads();
  for (int e = e0 + t; e < e1; e += 256) {
    if (sel[e]) {
      int i = atomicAdd(&nsel_s, 1);
      if (i < CCCAP) rc[i] = ((unsigned)(row[e] - base) << 16) | (unsigned)(col[e] - base);
      else novf = 1;
    }
  }
  __syncthreads();
  int ns = nsel_s < CCCAP ? nsel_s : CCCAP;
  int ovf = novf;
  for (int it = 0; it < CC_ITERS_; ++it) {
    for (int i = t; i < BLKG; i += 256) cur[i] = lab[i];
    if (t == 0) chg = 0;
    __syncthreads();
    for (int i = t; i < ns; i += 256) {
      unsigned v = rc[i]; int r = v >> 16, c = v & 0xffff;
      atomicMin(&cur[r], lab[c]);
      atomicMin(&cur[c], lab[r]);
    }
    if (ovf) {
      for (int e = e0 + t; e < e1; e += 256) {
        if (sel[e]) {
          int r = row[e] - base, c = col[e] - base;
          atomicMin(&cur[r], lab[c]);
          atomicMin(&cur[c], lab[r]);
        }
      }
    }
    __syncthreads();
    for (int i = t; i < BLKG; i += 256) {
      int v = cur[i]; v = cur[v]; v = cur[v]; v = cur[v];
      if (v != lab[i]) chg = 1;
      lab[i] = v;
    }
    __syncthreads();
    if (!chg) break;
  }
  for (int i = t; i < BLKG; i += 256) {
    int L = lab[i];
    lab_g[base + i] = base + L;
    cum[base + i] = (L == i) ? 1 : 0;
  }
}

// ---------------- multi-block inclusive scan ----------------

__global__ void k_scan1(int* __restrict__ d, int* __restrict__ parts, int n) {
  __shared__ int s[SCAN_B];
  int i = blockIdx.x * SCAN_B + threadIdx.x;
  int v = (i < n) ? d[i] : 0;
  s[threadIdx.x] = v; __syncthreads();
  for (int off = 1; off < SCAN_B; off <<= 1) {
    int t2 = (threadIdx.x >= off) ? s[threadIdx.x - off] : 0;
    __syncthreads();
    s[threadIdx.x] += t2;
    __syncthreads();
  }
  if (i < n) d[i] = s[threadIdx.x];
  if (threadIdx.x == SCAN_B - 1) parts[blockIdx.x] = s[SCAN_B - 1];
}

__global__ void k_scan2(int* __restrict__ parts, int nb) {
  __shared__ int s[SCAN_B];
  int v = ((int)threadIdx.x < nb) ? parts[threadIdx.x] : 0;
  s[threadIdx.x] = v; __syncthreads();
  for (int off = 1; off < SCAN_B; off <<= 1) {
    int t2 = (threadIdx.x >= off) ? s[threadIdx.x - off] : 0;
    __syncthreads();
    s[threadIdx.x] += t2;
    __syncthreads();
  }
  if ((int)threadIdx.x < nb) parts[threadIdx.x] = s[threadIdx.x];
}

__global__ void k_scan3(int* __restrict__ d, const int* __restrict__ parts, int n) {
  int i = blockIdx.x * SCAN_B + threadIdx.x;
  if (i < n && blockIdx.x > 0) d[i] += parts[blockIdx.x - 1];
}

// ---------------- comp / counts ----------------

__global__ void k_crep(const int* __restrict__ cum, int* __restrict__ crep) {
  int g = threadIdx.x;
  if (g <= B_) crep[g] = (g == 0) ? 0 : cum[g * BLKG - 1];
}

__global__ void k_comp(const int* __restrict__ cum, const int* __restrict__ lab,
                       int* __restrict__ comp) {
  int n = blockIdx.x * blockDim.x + threadIdx.x;
  if (n < N_) comp[n] = cum[lab[n]] - 1;
}

__global__ void k_cnt(const int* __restrict__ comp, const int* __restrict__ batch,
                      const int* __restrict__ xmask, int* __restrict__ cnt,
                      int* __restrict__ bsum, int* __restrict__ keep) {
  int n = blockIdx.x * blockDim.x + threadIdx.x;
  if (n >= N_) return;
  int c = comp[n];
  atomicAdd(&cnt[c], 1);
  atomicAdd(&bsum[c], batch[n]);
  if (!xmask[n]) atomicAdd(&keep[c], 1);
}

__global__ void k_batchout(const int* __restrict__ cnt, const int* __restrict__ bsum,
                           float* __restrict__ bout) {
  int c = blockIdx.x * blockDim.x + threadIdx.x;
  if (c >= N_) return;
  int ct = cnt[c];
  bout[c] = (float)(bsum[c] / (ct > 0 ? ct : 1));
}

// ---------------- EGIN conv: broadcast A-reads, no in-loop barriers ----------

__global__ __launch_bounds__(128) void k_agg(const float* __restrict__ x,
                                             const float* __restrict__ A,
                                             const float* __restrict__ score,
                                             const int* __restrict__ col,
                                             const int* __restrict__ rp,
                                             const int* __restrict__ sel,
                                             const float* __restrict__ W_edge,
                                             const float* __restrict__ epsp,
                                             float* __restrict__ hc) {
  __shared__ float sW[CE_ * CX_];
  int n = blockIdx.x, t = threadIdx.x;  // 128 threads
  for (int i = t; i < CE_ * CX_; i += 128) sW[i] = W_edge[i];
  __syncthreads();
  float acc = 0.f;
  int b = rp[n], e = rp[n + 1];
  for (int i = b; i < e; i++) {
    if (!sel[i]) continue;
    float sc = score[i];
    const float4* a4 = (const float4*)(A + (size_t)i * CE_);
    float m = x[(size_t)col[i] * CX_ + t];
#pragma unroll
    for (int q = 0; q < 8; q++) {
      float4 v = a4[q];   // all lanes same address -> wave broadcast
      m += (v.x * sc) * sW[(4 * q + 0) * CX_ + t];
      m += (v.y * sc) * sW[(4 * q + 1) * CX_ + t];
      m += (v.z * sc) * sW[(4 * q + 2) * CX_ + t];
      m += (v.w * sc) * sW[(4 * q + 3) * CX_ + t];
    }
    acc += fmaxf(m, 0.f);
  }
  hc[(size_t)n * CX_ + t] = (1.f + epsp[0]) * x[(size_t)n * CX_ + t] + acc;
}

template <bool RELU>
__global__ void k_gemm128(const float* __restrict__ X, const float* __restrict__ W,
                          const float* __restrict__ bias, float* __restrict__ Y) {
  __shared__ float sX[16 * CX_];
  int t = threadIdx.x;
  int r0 = blockIdx.x * 16;
  for (int i = t; i < 16 * CX_; i += 256) sX[i] = X[(size_t)r0 * CX_ + i];
  __syncthreads();
  int j = t & 127, rl = t >> 7;
  float acc[8];
  for (int i = 0; i < 8; i++) acc[i] = 0.f;
  for (int k = 0; k < CX_; k++) {
    float w = W[k * CX_ + j];
    for (int i = 0; i < 8; i++) acc[i] += sX[(rl + 2 * i) * CX_ + k] * w;
  }
  float b = bias[j];
  for (int i = 0; i < 8; i++) {
    float v = acc[i] + b;
    if (RELU) v = fmaxf(v, 0.f);
    Y[(size_t)(r0 + rl + 2 * i) * CX_ + j] = v;
  }
}

// ---------------- pooling: block per cluster, wave-parallel decode ----------

__global__ void k_nbits(const int* __restrict__ comp, unsigned int* __restrict__ nbits) {
  int n = blockIdx.x * blockDim.x + threadIdx.x;
  if (n >= N_) return;
  int c = comp[n];
  int j = n % BLKG;
  atomicOr(&nbits[(size_t)c * BITW + (j >> 5)], 1u << (j & 31));
}

__global__ __launch_bounds__(512) void k_pool2(const float* __restrict__ xc,
                                               const float* __restrict__ x,
                                               const unsigned int* __restrict__ nbits,
                                               const int* __restrict__ cnt,
                                               const int* __restrict__ bsum,
                                               const int* __restrict__ xmask,
                                               const int* __restrict__ keep,
                                               float* __restrict__ xout) {
  __shared__ int nodes[BLKG];
  __shared__ int nn;
  __shared__ float part[4 * CX_];
  int c = blockIdx.x, t = threadIdx.x;
  int ct = cnt[c];
  if (ct == 0) { if (t < CX_) xout[(size_t)c * CX_ + t] = 0.f; return; }
  if (t < 64) {
    int w = t;
    unsigned int word = (w < BITW) ? nbits[(size_t)c * BITW + w] : 0u;
    int pc = __popc(word);
    int sc = pc;
    for (int off = 1; off < 32; off <<= 1) {
      int o = __shfl_up(sc, off, 64);
      if (w >= off) sc += o;
    }
    int idx = sc - pc;
    int g = bsum[c] / ct;
    int nb = g * BLKG;
    while (word) {
      int j = __ffs(word) - 1; word &= word - 1;
      nodes[idx++] = nb + w * 32 + j;
    }
    if (w == BITW - 1) nn = sc;
  }
  __syncthreads();
  int ch = t & 127, sub = t >> 7;
  int kp = keep[c];
  float s = 0.f;
  int m = nn;
  for (int i = sub; i < m; i += 4) {
    int n = nodes[i];
    int xm = xmask[n];
    if (kp > 0) { if (!xm) s += x[(size_t)n * CX_ + ch]; }
    else        { if (xm)  s += xc[(size_t)n * CX_ + ch]; }
  }
  part[t] = s; __syncthreads();
  if (t < 256) part[t] += part[t + 256];
  __syncthreads();
  if (t < 128) xout[(size_t)c * CX_ + t] = part[t] + part[t + 128];
}

// ---------------- edge coalesce (presence bits -> rank -> run-compressed add) ----

__global__ void k_fillm1(float* __restrict__ p, int n) {
  int t = blockIdx.x * blockDim.x + threadIdx.x;
  if (t < n) p[t] = -1.0f;
}

__global__ void k_presbits(const int* __restrict__ row, const int* __restrict__ col,
                           const int* __restrict__ sel, const int* __restrict__ comp,
                           const int* __restrict__ crep, unsigned int* __restrict__ bits) {
  int e = blockIdx.x * blockDim.x + threadIdx.x;
  if (e >= E_ || sel[e]) return;
  int cu = comp[row[e]], cv = comp[col[e]];
  int g = row[e] / BLKG;
  int j = cv - crep[g];
  atomicOr(&bits[(size_t)cu * BITW + (j >> 5)], 1u << (j & 31));
}

__global__ void k_dcount(const unsigned int* __restrict__ bits, int* __restrict__ dscan) {
  int cu = blockIdx.x * blockDim.x + threadIdx.x;
  if (cu >= N_) return;
  int s = 0;
  for (int w = 0; w < BITW; w++) s += __popc(bits[(size_t)cu * BITW + w]);
  dscan[cu] = s;
}

__global__ void k_grank(const int* __restrict__ row, const int* __restrict__ col,
                        const int* __restrict__ sel, const int* __restrict__ comp,
                        const int* __restrict__ crep, const unsigned int* __restrict__ bits,
                        const int* __restrict__ dscan, int* __restrict__ grank) {
  int e = blockIdx.x * blockDim.x + threadIdx.x;
  if (e >= E_) return;
  if (sel[e]) { grank[e] = -1; return; }
  int cu = comp[row[e]], cv = comp[col[e]];
  int g = row[e] / BLKG;
  int j = cv - crep[g];
  int base = (cu > 0) ? dscan[cu - 1] : 0;
  int r = 0, wj = j >> 5;
  for (int w = 0; w < wj; w++) r += __popc(bits[(size_t)cu * BITW + w]);
  unsigned int mask = (1u << (j & 31)) - 1u;
  r += __popc(bits[(size_t)cu * BITW + wj] & mask);
  grank[e] = base + r;
}

__global__ void k_attr_r(const float* __restrict__ A, const float* __restrict__ score,
                         const int* __restrict__ grank, float* __restrict__ attr_out) {
  int t = blockIdx.x * blockDim.x + threadIdx.x;
  if (t >= E_) return;
  int w = t >> 5, k = t & 31;
  int e0 = w * 32, e1 = e0 + 32;
  if (e1 > E_) e1 = E_;
  float acc = 0.f; int cs = -1;
  for (int e = e0; e < e1; ++e) {
    int s = grank[e];
    if (s < 0) continue;
    float v = A[(size_t)e * CE_ + k] * score[e];
    if (s != cs) {
      if (cs >= 0) atomicAdd(&attr_out[(size_t)cs * CE_ + k], acc);
      cs = s; acc = v;
    } else acc += v;
  }
  if (cs >= 0) atomicAdd(&attr_out[(size_t)cs * CE_ + k], acc);
}

// block per cluster, wave-parallel bit expansion
__global__ __launch_bounds__(64) void k_eidx(const unsigned int* __restrict__ bits,
                                             const int* __restrict__ dscan,
                                             const int* __restrict__ cnt,
                                             const int* __restrict__ bsum,
                                             const int* __restrict__ crep,
                                             float* __restrict__ ei0,
                                             float* __restrict__ ei1) {
  int cu = blockIdx.x, t = threadIdx.x;
  int ct = cnt[cu];
  if (ct == 0) return;
  int w = t;
  unsigned int word = (w < BITW) ? bits[(size_t)cu * BITW + w] : 0u;
  int pc = __popc(word);
  int sc = pc;
  for (int off = 1; off < 32; off <<= 1) {
    int o = __shfl_up(sc, off, 64);
    if (w >= off) sc += o;
  }
  int base = (cu > 0) ? dscan[cu - 1] : 0;
  int idx = base + sc - pc;
  int g = bsum[cu] / ct;
  int cb = crep[g];
  float fcu = (float)cu;
  while (word) {
    int j = __ffs(word) - 1; word &= word - 1;
    ei0[idx] = fcu;
    ei1[idx] = (float)(cb + w * 32 + j);
    idx++;
  }
}

// ---------------- global pool + BN ----------------

__global__ void k_xg(const float* __restrict__ xout, const int* __restrict__ crep,
                     float* __restrict__ xg_raw) {
  int b = blockIdx.x, ch = threadIdx.x;
  float s = 0.f;
  int c0 = crep[b], c1 = crep[b + 1];
  for (int c = c0; c < c1; c++) s += xout[(size_t)c * CX_ + ch];
  xg_raw[b * CX_ + ch] = s;
}

__global__ void k_xgbn(const float* __restrict__ xg_raw, const float* __restrict__ g,
                       const float* __restrict__ bb, float* __restrict__ xg) {
  int ch = threadIdx.x;
  float mu = 0.f;
  for (int b = 0; b < B_; b++) mu += xg_raw[b * CX_ + ch];
  mu /= (float)B_;
  float var = 0.f;
  for (int b = 0; b < B_; b++) { float d = xg_raw[b * CX_ + ch] - mu; var += d * d; }
  var /= (float)B_;
  float sc = g[ch] / sqrtf(var + BNEPS_);
  for (int b = 0; b < B_; b++)
    xg[b * CX_ + ch] = (xg_raw[b * CX_ + ch] - mu) * sc + bb[ch];
}

// ---------------- launch ----------------

extern "C" void kernel_launch(void* const* d_in, const int* in_sizes, int n_in,
                              void* d_out, int out_size, void* d_ws, size_t ws_size,
                              hipStream_t stream) {
  const float* x      = (const float*)d_in[0];
  const int*   ei     = (const int*)d_in[1];
  const int*   row    = ei;
  const int*   col    = ei + E_;
  const float* eattr  = (const float*)d_in[2];
  const int*   batch  = (const int*)d_in[3];
  const float* S      = (const float*)d_in[4];
  const float* We     = (const float*)d_in[5];
  const float* be     = (const float*)d_in[6];
  const float* bn_e_g = (const float*)d_in[7];
  const float* bn_e_b = (const float*)d_in[8];
  const float* W_edge = (const float*)d_in[9];
  const float* epsp   = (const float*)d_in[10];
  const float* W1     = (const float*)d_in[11];
  const float* b1     = (const float*)d_in[12];
  const float* W2     = (const float*)d_in[13];
  const float* b2     = (const float*)d_in[14];
  const float* bn_g   = (const float*)d_in[15];
  const float* bn_b   = (const float*)d_in[16];

  float* xout     = (float*)d_out;
  float* ei0      = (float*)d_out + (size_t)N_ * CX_;
  float* ei1      = ei0 + E_;
  float* attr_out = (float*)d_out + (size_t)N_ * CX_ + 2 * (size_t)E_;
  float* bout     = (float*)d_out + (size_t)N_ * CX_ + 2 * (size_t)E_ + (size_t)E_ * CE_;
  float* xg       = (float*)d_out + (size_t)N_ * CX_ + 2 * (size_t)E_ + (size_t)E_ * CE_ + N_;

  char* w = (char*)d_ws;
  size_t off = 0;
  auto alloc = [&](size_t bytes) -> void* {
    void* p = w + off;
    off += (bytes + 511) & ~(size_t)511;
    return p;
  };
  double* bnacc = (double*)alloc(64 * 8);
  float* A      = (float*)alloc((size_t)E_ * CE_ * 4);
  float* Hb     = (float*)alloc((size_t)E_ * CE_ * 4);
  float* tgt    = (float*)alloc((size_t)N_ * CE_ * 4);
  float* hc     = (float*)alloc((size_t)N_ * CX_ * 4);
  float* h1     = (float*)alloc((size_t)N_ * CX_ * 4);
  int*   pos    = (int*)alloc((size_t)E_ * 4);   // later reused as grank
  float* tdot   = (float*)alloc((size_t)E_ * 4);
  float* score  = (float*)alloc((size_t)E_ * 4);
  int*   sel    = (int*)alloc((size_t)E_ * 4);
  int*   rp     = (int*)alloc((size_t)(N_ + 1) * 4);
  int*   cum    = (int*)alloc((size_t)N_ * 4);
  int*   comp   = (int*)alloc((size_t)N_ * 4);
  int*   lab    = (int*)alloc((size_t)N_ * 4);
  int*   cnt    = (int*)alloc((size_t)N_ * 4);
  int*   bsum   = (int*)alloc((size_t)N_ * 4);
  int*   keep   = (int*)alloc((size_t)N_ * 4);
  int*   xmask  = (int*)alloc((size_t)N_ * 4);
  int*   dscan  = (int*)alloc((size_t)N_ * 4);
  unsigned int* bits  = (unsigned int*)alloc((size_t)N_ * BITW * 4);
  unsigned int* nbits = (unsigned int*)alloc((size_t)N_ * BITW * 4);
  int*   parts  = (int*)alloc(1024 * 4);
  int*   crep   = (int*)alloc((size_t)(B_ + 1) * 4);
  float* gmean  = (float*)alloc((size_t)B_ * 4);
  float* xg_raw = (float*)alloc((size_t)B_ * CX_ * 4);
  float* scale  = (float*)alloc(CE_ * 4);
  float* shift  = (float*)alloc(CE_ * 4);
  float* snorm  = (float*)alloc(4);
  if (off > ws_size) return;

  const int NB_N = gr(N_, SCAN_B);   // 45

  // ---- zero/init ----
  hipMemsetAsync(bnacc, 0, 64 * 8, stream);
  hipMemsetAsync(cnt, 0, (size_t)N_ * 4, stream);
  hipMemsetAsync(bsum, 0, (size_t)N_ * 4, stream);
  hipMemsetAsync(keep, 0, (size_t)N_ * 4, stream);
  hipMemsetAsync(xmask, 0, (size_t)N_ * 4, stream);
  hipMemsetAsync(bits, 0, (size_t)N_ * BITW * 4, stream);
  hipMemsetAsync(nbits, 0, (size_t)N_ * BITW * 4, stream);
  hipMemsetAsync(attr_out, 0, (size_t)E_ * CE_ * 4, stream);
  k_fillm1<<<gr(2 * E_, 256), 256, 0, stream>>>(ei0, 2 * E_);

  // ---- edge prop + mlp_e (fused) ----
  k_rowptr<<<gr(N_ + 1, 256), 256, 0, stream>>>(row, rp);
  k_pos<<<gr(E_, 256), 256, 0, stream>>>(row, col, pos);
  k_tgt<<<gr(N_ * CE_, 256), 256, 0, stream>>>(eattr, pos, rp, tgt);
  k_mlp2<<<E_ / 8, 256, 0, stream>>>(eattr, tgt, row, We, be, Hb);
  k_bnstats<<<512, 256, 0, stream>>>(Hb, bnacc);
  k_bnfin<<<1, 64, 0, stream>>>(bnacc, bn_e_g, bn_e_b, S, scale, shift, snorm);
  k_bnT<<<gr(E_, 256), 256, 0, stream>>>(Hb, scale, shift, S, A, tdot);

  // ---- score / selection ----
  k_score<<<gr(E_, 256), 256, 0, stream>>>(tdot, pos, snorm, score);
  k_gmean<<<B_, 256, 0, stream>>>(score, rp, gmean);
  k_sel<<<gr(E_, 256), 256, 0, stream>>>(score, gmean, row, sel, xmask);

  // ---- connected components (LDS, early-exit) ----
  k_cc<<<B_, 256, 0, stream>>>(rp, row, col, sel, lab, cum);
  k_scan1<<<NB_N, SCAN_B, 0, stream>>>(cum, parts, N_);
  k_scan2<<<1, SCAN_B, 0, stream>>>(parts, NB_N);
  k_scan3<<<NB_N, SCAN_B, 0, stream>>>(cum, parts, N_);
  k_crep<<<1, 128, 0, stream>>>(cum, crep);
  k_comp<<<gr(N_, 256), 256, 0, stream>>>(cum, lab, comp);
  k_cnt<<<gr(N_, 256), 256, 0, stream>>>(comp, batch, xmask, cnt, bsum, keep);
  k_batchout<<<gr(N_, 256), 256, 0, stream>>>(cnt, bsum, bout);

  // ---- EGIN conv ----
  k_agg<<<N_, 128, 0, stream>>>(x, A, score, col, rp, sel, W_edge, epsp, hc);
  k_gemm128<true><<<N_ / 16, 256, 0, stream>>>(hc, W1, b1, h1);
  k_gemm128<false><<<N_ / 16, 256, 0, stream>>>(h1, W2, b2, hc);  // hc = x_conv

  // ---- pooling ----
  k_nbits<<<gr(N_, 256), 256, 0, stream>>>(comp, nbits);
  k_pool2<<<N_, 512, 0, stream>>>(hc, x, nbits, cnt, bsum, xmask, keep, xout);

  // ---- edge coalesce ----
  k_presbits<<<gr(E_, 256), 256, 0, stream>>>(row, col, sel, comp, crep, bits);
  k_dcount<<<gr(N_, 256), 256, 0, stream>>>(bits, dscan);
  k_scan1<<<NB_N, SCAN_B, 0, stream>>>(dscan, parts, N_);
  k_scan2<<<1, SCAN_B, 0, stream>>>(parts, NB_N);
  k_scan3<<<NB_N, SCAN_B, 0, stream>>>(dscan, parts, N_);
  k_grank<<<gr(E_, 256), 256, 0, stream>>>(row, col, sel, comp, crep, bits, dscan, pos);
  k_attr_r<<<gr(E_, 256), 256, 0, stream>>>(A, score, pos, attr_out);
  k_eidx<<<N_, 64, 0, stream>>>(bits, dscan, cnt, bsum, crep, ei0, ei1);

  // ---- global pool + BN ----
  k_xg<<<B_, CX_, 0, stream>>>(xout, crep, xg_raw);
  k_xgbn<<<1, CX_, 0, stream>>>(xg_raw, bn_g, bn_b, xg);
}

// Round 9
// 1050.527 us; speedup vs baseline: 4.7490x; 1.1617x over previous
//
#include <hip/hip_runtime.h>
#include <cstdint>
#include <cstddef>

#define N_ 46080
#define B_ 64
#define BLKG 720
#define E_ 400000
#define CX_ 128
#define CE_ 32
#define BNEPS_ 1e-5f
#define CC_ITERS_ 40
#define BITW 24   // words of presence bitmask (768 bits >= 720)
#define SCAN_B 1024
#define CCCAP 7424

static inline int gr(int n, int b) { return (n + b - 1) / b; }

// ---------------- CSR / reverse-edge ----------------

__global__ void k_rowptr(const int* __restrict__ row, int* __restrict__ rp) {
  int n = blockIdx.x * blockDim.x + threadIdx.x;
  if (n > N_) return;
  int lo = 0, hi = E_;
  while (lo < hi) { int mid = (lo + hi) >> 1; if (row[mid] < n) lo = mid + 1; else hi = mid; }
  rp[n] = lo;
}

// reverse edge of (r,c) lives in row-block of c; search col[] there (~4 iters)
__global__ void k_pos(const int* __restrict__ row, const int* __restrict__ col,
                      const int* __restrict__ rp, int* __restrict__ pos) {
  int e = blockIdx.x * blockDim.x + threadIdx.x;
  if (e >= E_) return;
  int r = row[e], c = col[e];
  int lo = rp[c], hi = rp[c + 1] - 1;
  while (lo < hi) {
    int mid = (lo + hi) >> 1;
    if (col[mid] < r) lo = mid + 1; else hi = mid;
  }
  pos[e] = lo;
}

__global__ void k_tgt(const float* __restrict__ attr, const int* __restrict__ pos,
                      const int* __restrict__ rp, float* __restrict__ tgt) {
  int t = blockIdx.x * blockDim.x + threadIdx.x;
  if (t >= N_ * CE_) return;
  int n = t / CE_, k = t % CE_;
  float s = 0.f;
  int b = rp[n], e = rp[n + 1];
  for (int i = b; i < e; i++) s += attr[(size_t)pos[i] * CE_ + k];
  tgt[t] = s;
}

// ---------------- fused edge_prop + Linear(32->32) ----------------

__global__ void k_mlp2(const float* __restrict__ attr, const float* __restrict__ tgt,
                       const int* __restrict__ row, const float* __restrict__ We,
                       const float* __restrict__ be, float* __restrict__ H) {
  __shared__ float sWe[CE_ * CE_];
  __shared__ float sA[8 * CE_];
  int t = threadIdx.x;
  for (int i = t; i < CE_ * CE_; i += 256) sWe[i] = We[i];
  int e0 = blockIdx.x * 8;
  for (int i = t; i < 8 * CE_; i += 256) {
    int el = i >> 5, ki = i & 31;
    int e = e0 + el;
    sA[i] = tgt[(size_t)row[e] * CE_ + ki] + attr[(size_t)e * CE_ + ki];
  }
  __syncthreads();
  int el = t >> 5, j = t & 31;
  float acc = be[j];
  for (int k = 0; k < CE_; k++) acc += sA[el * CE_ + k] * sWe[k * CE_ + j];
  H[(size_t)(e0 + el) * CE_ + j] = acc;
}

__global__ void k_bnstats(const float* __restrict__ H, double* __restrict__ acc) {
  int t = threadIdx.x; int ch = t & 31, grp = t >> 5;
  double s = 0.0, s2 = 0.0;
  for (int e = blockIdx.x * 8 + grp; e < E_; e += gridDim.x * 8) {
    double v = H[(size_t)e * CE_ + ch];
    s += v; s2 += v * v;
  }
  __shared__ double sh[256], sh2[256];
  sh[t] = s; sh2[t] = s2; __syncthreads();
  for (int off = 128; off >= 32; off >>= 1) {
    if (t < off) { sh[t] += sh[t + off]; sh2[t] += sh2[t + off]; }
    __syncthreads();
  }
  if (t < 32) { atomicAdd(&acc[ch], sh[t]); atomicAdd(&acc[32 + ch], sh2[t]); }
}

__global__ void k_bnfin(const double* __restrict__ acc, const float* __restrict__ g,
                        const float* __restrict__ b, const float* __restrict__ S,
                        float* __restrict__ scale, float* __restrict__ shift,
                        float* __restrict__ snorm) {
  int t = threadIdx.x;
  if (t < CE_) {
    double mu = acc[t] / (double)E_;
    double var = acc[32 + t] / (double)E_ - mu * mu;
    float sc = (float)((double)g[t] / sqrt(var + 1e-5));
    scale[t] = sc;
    shift[t] = b[t] - (float)mu * sc;
  }
  if (t == 0) {
    float s = 0.f;
    for (int k = 0; k < CE_; k++) s += S[k] * S[k];
    *snorm = sqrtf(s);
  }
}

// ---------------- fused BN-apply + ReLU + S-dot ----------------

__global__ void k_bnT(const float* __restrict__ H, const float* __restrict__ scale,
                      const float* __restrict__ shift, const float* __restrict__ S,
                      float* __restrict__ A, float* __restrict__ tdot) {
  __shared__ float ssc[CE_], ssh[CE_], sS[CE_];
  if (threadIdx.x < CE_) {
    ssc[threadIdx.x] = scale[threadIdx.x];
    ssh[threadIdx.x] = shift[threadIdx.x];
    sS[threadIdx.x] = S[threadIdx.x];
  }
  __syncthreads();
  int e = blockIdx.x * blockDim.x + threadIdx.x;
  if (e >= E_) return;
  const float4* h4 = (const float4*)(H + (size_t)e * CE_);
  float4* a4 = (float4*)(A + (size_t)e * CE_);
  float s = 0.f;
  for (int q = 0; q < 8; q++) {
    float4 v = h4[q];
    float4 r;
    r.x = fmaxf(v.x * ssc[q * 4 + 0] + ssh[q * 4 + 0], 0.f);
    r.y = fmaxf(v.y * ssc[q * 4 + 1] + ssh[q * 4 + 1], 0.f);
    r.z = fmaxf(v.z * ssc[q * 4 + 2] + ssh[q * 4 + 2], 0.f);
    r.w = fmaxf(v.w * ssc[q * 4 + 3] + ssh[q * 4 + 3], 0.f);
    a4[q] = r;
    s += r.x * sS[q * 4 + 0] + r.y * sS[q * 4 + 1] + r.z * sS[q * 4 + 2] + r.w * sS[q * 4 + 3];
  }
  tdot[e] = s;
}

__global__ void k_score(const float* __restrict__ tdot, const int* __restrict__ pos,
                        const float* __restrict__ snorm, float* __restrict__ score) {
  int e = blockIdx.x * blockDim.x + threadIdx.x;
  if (e >= E_) return;
  float z = (tdot[e] + tdot[pos[e]]) / (*snorm);
  score[e] = 1.f / (1.f + expf(-z));
}

__global__ void k_gmean(const float* __restrict__ score, const int* __restrict__ rp,
                        float* __restrict__ gmean) {
  int g = blockIdx.x; int t = threadIdx.x;
  int b = rp[g * BLKG], e = rp[(g + 1) * BLKG];
  float s = 0.f;
  for (int i = b + t; i < e; i += 256) s += score[i];
  __shared__ float sh[256];
  sh[t] = s; __syncthreads();
  for (int off = 128; off; off >>= 1) { if (t < off) sh[t] += sh[t + off]; __syncthreads(); }
  if (t == 0) gmean[g] = sh[0] / (float)(e - b);
}

__global__ void k_sel(const float* __restrict__ score, const float* __restrict__ gmean,
                      const int* __restrict__ row,
                      int* __restrict__ sel, int* __restrict__ xmask) {
  int e = blockIdx.x * blockDim.x + threadIdx.x;
  if (e >= E_) return;
  int r = row[e];
  int g = r / BLKG;
  float s = score[e];
  int v = (s <= 0.5f) && (s < gmean[g]);
  sel[e] = v;
  if (v) atomicOr(&xmask[r], 1);
}

// ---------------- connected components: LDS, early-exit on convergence -------

__global__ __launch_bounds__(256) void k_cc(const int* __restrict__ rp,
                                            const int* __restrict__ row,
                                            const int* __restrict__ col,
                                            const int* __restrict__ sel,
                                            int* __restrict__ lab_g,
                                            int* __restrict__ cum) {
  __shared__ int lab[BLKG], cur[BLKG];
  __shared__ unsigned int rc[CCCAP];
  __shared__ int nsel_s, novf, chg;
  int g = blockIdx.x, t = threadIdx.x;
  int base = g * BLKG;
  int e0 = rp[base], e1 = rp[base + BLKG];
  if (t == 0) { nsel_s = 0; novf = 0; }
  for (int i = t; i < BLKG; i += 256) lab[i] = i;
  __syncthreads();
  for (int e = e0 + t; e < e1; e += 256) {
    if (sel[e]) {
      int i = atomicAdd(&nsel_s, 1);
      if (i < CCCAP) rc[i] = ((unsigned)(row[e] - base) << 16) | (unsigned)(col[e] - base);
      else novf = 1;
    }
  }
  __syncthreads();
  int ns = nsel_s < CCCAP ? nsel_s : CCCAP;
  int ovf = novf;
  for (int it = 0; it < CC_ITERS_; ++it) {
    for (int i = t; i < BLKG; i += 256) cur[i] = lab[i];
    if (t == 0) chg = 0;
    __syncthreads();
    for (int i = t; i < ns; i += 256) {
      unsigned v = rc[i]; int r = v >> 16, c = v & 0xffff;
      atomicMin(&cur[r], lab[c]);
      atomicMin(&cur[c], lab[r]);
    }
    if (ovf) {
      for (int e = e0 + t; e < e1; e += 256) {
        if (sel[e]) {
          int r = row[e] - base, c = col[e] - base;
          atomicMin(&cur[r], lab[c]);
          atomicMin(&cur[c], lab[r]);
        }
      }
    }
    __syncthreads();
    for (int i = t; i < BLKG; i += 256) {
      int v = cur[i]; v = cur[v]; v = cur[v]; v = cur[v];
      if (v != lab[i]) chg = 1;
      lab[i] = v;
    }
    __syncthreads();
    if (!chg) break;
  }
  for (int i = t; i < BLKG; i += 256) {
    int L = lab[i];
    lab_g[base + i] = base + L;
    cum[base + i] = (L == i) ? 1 : 0;
  }
}

// ---------------- multi-block inclusive scan ----------------

__global__ void k_scan1(int* __restrict__ d, int* __restrict__ parts, int n) {
  __shared__ int s[SCAN_B];
  int i = blockIdx.x * SCAN_B + threadIdx.x;
  int v = (i < n) ? d[i] : 0;
  s[threadIdx.x] = v; __syncthreads();
  for (int off = 1; off < SCAN_B; off <<= 1) {
    int t2 = (threadIdx.x >= off) ? s[threadIdx.x - off] : 0;
    __syncthreads();
    s[threadIdx.x] += t2;
    __syncthreads();
  }
  if (i < n) d[i] = s[threadIdx.x];
  if (threadIdx.x == SCAN_B - 1) parts[blockIdx.x] = s[SCAN_B - 1];
}

// scan1 variant: value = popcount of a BITW-word bitmask row (folds k_dcount)
__global__ void k_scan1d(const unsigned int* __restrict__ bits, int* __restrict__ d,
                         int* __restrict__ parts, int n) {
  __shared__ int s[SCAN_B];
  int i = blockIdx.x * SCAN_B + threadIdx.x;
  int v = 0;
  if (i < n) {
    for (int w = 0; w < BITW; w++) v += __popc(bits[(size_t)i * BITW + w]);
  }
  s[threadIdx.x] = v; __syncthreads();
  for (int off = 1; off < SCAN_B; off <<= 1) {
    int t2 = (threadIdx.x >= off) ? s[threadIdx.x - off] : 0;
    __syncthreads();
    s[threadIdx.x] += t2;
    __syncthreads();
  }
  if (i < n) d[i] = s[threadIdx.x];
  if (threadIdx.x == SCAN_B - 1) parts[blockIdx.x] = s[SCAN_B - 1];
}

__global__ void k_scan2(int* __restrict__ parts, int nb) {
  __shared__ int s[SCAN_B];
  int v = ((int)threadIdx.x < nb) ? parts[threadIdx.x] : 0;
  s[threadIdx.x] = v; __syncthreads();
  for (int off = 1; off < SCAN_B; off <<= 1) {
    int t2 = (threadIdx.x >= off) ? s[threadIdx.x - off] : 0;
    __syncthreads();
    s[threadIdx.x] += t2;
    __syncthreads();
  }
  if ((int)threadIdx.x < nb) parts[threadIdx.x] = s[threadIdx.x];
}

__global__ void k_scan3(int* __restrict__ d, const int* __restrict__ parts, int n) {
  int i = blockIdx.x * SCAN_B + threadIdx.x;
  if (i < n && blockIdx.x > 0) d[i] += parts[blockIdx.x - 1];
}

// scan3 variant for cum: also emits crep (folds k_crep)
__global__ void k_scan3c(int* __restrict__ d, const int* __restrict__ parts, int n,
                         int* __restrict__ crep) {
  int i = blockIdx.x * SCAN_B + threadIdx.x;
  if (i >= n) return;
  int v = d[i];
  if (blockIdx.x > 0) { v += parts[blockIdx.x - 1]; d[i] = v; }
  if (i == 0) crep[0] = 0;
  int i1 = i + 1;
  if (i1 % BLKG == 0) crep[i1 / BLKG] = v;
}

// ---------------- comp + counts + node bitmask (fused per-node pass) --------

__global__ void k_comp2(const int* __restrict__ cum, const int* __restrict__ lab,
                        const int* __restrict__ batch, const int* __restrict__ xmask,
                        int* __restrict__ comp, int* __restrict__ cnt,
                        int* __restrict__ bsum, int* __restrict__ keep,
                        unsigned int* __restrict__ nbits) {
  int n = blockIdx.x * blockDim.x + threadIdx.x;
  if (n >= N_) return;
  int c = cum[lab[n]] - 1;
  comp[n] = c;
  atomicAdd(&cnt[c], 1);
  atomicAdd(&bsum[c], batch[n]);
  if (!xmask[n]) atomicAdd(&keep[c], 1);
  int j = n % BLKG;
  atomicOr(&nbits[(size_t)c * BITW + (j >> 5)], 1u << (j & 31));
}

// ---------------- EGIN conv: broadcast A-reads, no in-loop barriers ----------

__global__ __launch_bounds__(128) void k_agg(const float* __restrict__ x,
                                             const float* __restrict__ A,
                                             const float* __restrict__ score,
                                             const int* __restrict__ col,
                                             const int* __restrict__ rp,
                                             const int* __restrict__ sel,
                                             const float* __restrict__ W_edge,
                                             const float* __restrict__ epsp,
                                             float* __restrict__ hc) {
  __shared__ float sW[CE_ * CX_];
  int n = blockIdx.x, t = threadIdx.x;  // 128 threads
  for (int i = t; i < CE_ * CX_; i += 128) sW[i] = W_edge[i];
  __syncthreads();
  float acc = 0.f;
  int b = rp[n], e = rp[n + 1];
  for (int i = b; i < e; i++) {
    if (!sel[i]) continue;
    float sc = score[i];
    const float4* a4 = (const float4*)(A + (size_t)i * CE_);
    float m = x[(size_t)col[i] * CX_ + t];
#pragma unroll
    for (int q = 0; q < 8; q++) {
      float4 v = a4[q];   // all lanes same address -> wave broadcast
      m += (v.x * sc) * sW[(4 * q + 0) * CX_ + t];
      m += (v.y * sc) * sW[(4 * q + 1) * CX_ + t];
      m += (v.z * sc) * sW[(4 * q + 2) * CX_ + t];
      m += (v.w * sc) * sW[(4 * q + 3) * CX_ + t];
    }
    acc += fmaxf(m, 0.f);
  }
  hc[(size_t)n * CX_ + t] = (1.f + epsp[0]) * x[(size_t)n * CX_ + t] + acc;
}

template <bool RELU>
__global__ void k_gemm128(const float* __restrict__ X, const float* __restrict__ W,
                          const float* __restrict__ bias, float* __restrict__ Y) {
  __shared__ float sX[16 * CX_];
  int t = threadIdx.x;
  int r0 = blockIdx.x * 16;
  for (int i = t; i < 16 * CX_; i += 256) sX[i] = X[(size_t)r0 * CX_ + i];
  __syncthreads();
  int j = t & 127, rl = t >> 7;
  float acc[8];
  for (int i = 0; i < 8; i++) acc[i] = 0.f;
  for (int k = 0; k < CX_; k++) {
    float w = W[k * CX_ + j];
    for (int i = 0; i < 8; i++) acc[i] += sX[(rl + 2 * i) * CX_ + k] * w;
  }
  float b = bias[j];
  for (int i = 0; i < 8; i++) {
    float v = acc[i] + b;
    if (RELU) v = fmaxf(v, 0.f);
    Y[(size_t)(r0 + rl + 2 * i) * CX_ + j] = v;
  }
}

// ---------------- pooling: block per cluster, wave-parallel decode -----------
// also emits batch_out (folds k_batchout)

__global__ __launch_bounds__(512) void k_pool2(const float* __restrict__ xc,
                                               const float* __restrict__ x,
                                               const unsigned int* __restrict__ nbits,
                                               const int* __restrict__ cnt,
                                               const int* __restrict__ bsum,
                                               const int* __restrict__ xmask,
                                               const int* __restrict__ keep,
                                               float* __restrict__ xout,
                                               float* __restrict__ bout) {
  __shared__ int nodes[BLKG];
  __shared__ int nn;
  __shared__ float part[4 * CX_];
  int c = blockIdx.x, t = threadIdx.x;
  int ct = cnt[c];
  if (ct == 0) {
    if (t < CX_) xout[(size_t)c * CX_ + t] = 0.f;
    if (t == 0) bout[c] = 0.f;
    return;
  }
  int g = bsum[c] / ct;
  if (t == 0) bout[c] = (float)g;
  if (t < 64) {
    int w = t;
    unsigned int word = (w < BITW) ? nbits[(size_t)c * BITW + w] : 0u;
    int pc = __popc(word);
    int sc = pc;
    for (int off = 1; off < 32; off <<= 1) {
      int o = __shfl_up(sc, off, 64);
      if (w >= off) sc += o;
    }
    int idx = sc - pc;
    int nb = g * BLKG;
    while (word) {
      int j = __ffs(word) - 1; word &= word - 1;
      nodes[idx++] = nb + w * 32 + j;
    }
    if (w == BITW - 1) nn = sc;
  }
  __syncthreads();
  int ch = t & 127, sub = t >> 7;
  int kp = keep[c];
  float s = 0.f;
  int m = nn;
  for (int i = sub; i < m; i += 4) {
    int n = nodes[i];
    int xm = xmask[n];
    if (kp > 0) { if (!xm) s += x[(size_t)n * CX_ + ch]; }
    else        { if (xm)  s += xc[(size_t)n * CX_ + ch]; }
  }
  part[t] = s; __syncthreads();
  if (t < 256) part[t] += part[t + 256];
  __syncthreads();
  if (t < 128) xout[(size_t)c * CX_ + t] = part[t] + part[t + 128];
}

// ---------------- edge coalesce (presence bits -> rank -> run-compressed add) ----

__global__ void k_fillm1(float* __restrict__ p, int n) {
  int t = blockIdx.x * blockDim.x + threadIdx.x;
  if (t < n) p[t] = -1.0f;
}

__global__ void k_presbits(const int* __restrict__ row, const int* __restrict__ col,
                           const int* __restrict__ sel, const int* __restrict__ comp,
                           const int* __restrict__ crep, unsigned int* __restrict__ bits) {
  int e = blockIdx.x * blockDim.x + threadIdx.x;
  if (e >= E_ || sel[e]) return;
  int cu = comp[row[e]], cv = comp[col[e]];
  int g = row[e] / BLKG;
  int j = cv - crep[g];
  atomicOr(&bits[(size_t)cu * BITW + (j >> 5)], 1u << (j & 31));
}

__global__ void k_grank(const int* __restrict__ row, const int* __restrict__ col,
                        const int* __restrict__ sel, const int* __restrict__ comp,
                        const int* __restrict__ crep, const unsigned int* __restrict__ bits,
                        const int* __restrict__ dscan, int* __restrict__ grank) {
  int e = blockIdx.x * blockDim.x + threadIdx.x;
  if (e >= E_) return;
  if (sel[e]) { grank[e] = -1; return; }
  int cu = comp[row[e]], cv = comp[col[e]];
  int g = row[e] / BLKG;
  int j = cv - crep[g];
  int base = (cu > 0) ? dscan[cu - 1] : 0;
  int r = 0, wj = j >> 5;
  for (int w = 0; w < wj; w++) r += __popc(bits[(size_t)cu * BITW + w]);
  unsigned int mask = (1u << (j & 31)) - 1u;
  r += __popc(bits[(size_t)cu * BITW + wj] & mask);
  grank[e] = base + r;
}

__global__ void k_attr_r(const float* __restrict__ A, const float* __restrict__ score,
                         const int* __restrict__ grank, float* __restrict__ attr_out) {
  int t = blockIdx.x * blockDim.x + threadIdx.x;
  if (t >= E_) return;
  int w = t >> 5, k = t & 31;
  int e0 = w * 32, e1 = e0 + 32;
  if (e1 > E_) e1 = E_;
  float acc = 0.f; int cs = -1;
  for (int e = e0; e < e1; ++e) {
    int s = grank[e];
    if (s < 0) continue;
    float v = A[(size_t)e * CE_ + k] * score[e];
    if (s != cs) {
      if (cs >= 0) atomicAdd(&attr_out[(size_t)cs * CE_ + k], acc);
      cs = s; acc = v;
    } else acc += v;
  }
  if (cs >= 0) atomicAdd(&attr_out[(size_t)cs * CE_ + k], acc);
}

// block per cluster, wave-parallel bit expansion
__global__ __launch_bounds__(64) void k_eidx(const unsigned int* __restrict__ bits,
                                             const int* __restrict__ dscan,
                                             const int* __restrict__ cnt,
                                             const int* __restrict__ bsum,
                                             const int* __restrict__ crep,
                                             float* __restrict__ ei0,
                                             float* __restrict__ ei1) {
  int cu = blockIdx.x, t = threadIdx.x;
  int ct = cnt[cu];
  if (ct == 0) return;
  int w = t;
  unsigned int word = (w < BITW) ? bits[(size_t)cu * BITW + w] : 0u;
  int pc = __popc(word);
  int sc = pc;
  for (int off = 1; off < 32; off <<= 1) {
    int o = __shfl_up(sc, off, 64);
    if (w >= off) sc += o;
  }
  int base = (cu > 0) ? dscan[cu - 1] : 0;
  int idx = base + sc - pc;
  int g = bsum[cu] / ct;
  int cb = crep[g];
  float fcu = (float)cu;
  while (word) {
    int j = __ffs(word) - 1; word &= word - 1;
    ei0[idx] = fcu;
    ei1[idx] = (float)(cb + w * 32 + j);
    idx++;
  }
}

// ---------------- global pool + BN ----------------
// 8 cluster-subgroups x 128 channels, LDS reduce: parallel + pipelined loads

__global__ __launch_bounds__(1024) void k_xg(const float* __restrict__ xout,
                                             const int* __restrict__ crep,
                                             float* __restrict__ xg_raw) {
  __shared__ float part[1024];
  int b = blockIdx.x, t = threadIdx.x;
  int ch = t & 127, sub = t >> 7;   // 8 subs
  int c0 = crep[b], c1 = crep[b + 1];
  float s = 0.f;
  for (int c = c0 + sub; c < c1; c += 8) s += xout[(size_t)c * CX_ + ch];
  part[t] = s; __syncthreads();
  if (t < 512) part[t] += part[t + 512];
  __syncthreads();
  if (t < 256) part[t] += part[t + 256];
  __syncthreads();
  if (t < 128) xg_raw[b * CX_ + t] = part[t] + part[t + 128];
}

__global__ void k_xgbn(const float* __restrict__ xg_raw, const float* __restrict__ g,
                       const float* __restrict__ bb, float* __restrict__ xg) {
  int ch = threadIdx.x;
  float mu = 0.f;
  for (int b = 0; b < B_; b++) mu += xg_raw[b * CX_ + ch];
  mu /= (float)B_;
  float var = 0.f;
  for (int b = 0; b < B_; b++) { float d = xg_raw[b * CX_ + ch] - mu; var += d * d; }
  var /= (float)B_;
  float sc = g[ch] / sqrtf(var + BNEPS_);
  for (int b = 0; b < B_; b++)
    xg[b * CX_ + ch] = (xg_raw[b * CX_ + ch] - mu) * sc + bb[ch];
}

// ---------------- launch ----------------

extern "C" void kernel_launch(void* const* d_in, const int* in_sizes, int n_in,
                              void* d_out, int out_size, void* d_ws, size_t ws_size,
                              hipStream_t stream) {
  const float* x      = (const float*)d_in[0];
  const int*   ei     = (const int*)d_in[1];
  const int*   row    = ei;
  const int*   col    = ei + E_;
  const float* eattr  = (const float*)d_in[2];
  const int*   batch  = (const int*)d_in[3];
  const float* S      = (const float*)d_in[4];
  const float* We     = (const float*)d_in[5];
  const float* be     = (const float*)d_in[6];
  const float* bn_e_g = (const float*)d_in[7];
  const float* bn_e_b = (const float*)d_in[8];
  const float* W_edge = (const float*)d_in[9];
  const float* epsp   = (const float*)d_in[10];
  const float* W1     = (const float*)d_in[11];
  const float* b1     = (const float*)d_in[12];
  const float* W2     = (const float*)d_in[13];
  const float* b2     = (const float*)d_in[14];
  const float* bn_g   = (const float*)d_in[15];
  const float* bn_b   = (const float*)d_in[16];

  float* xout     = (float*)d_out;
  float* ei0      = (float*)d_out + (size_t)N_ * CX_;
  float* ei1      = ei0 + E_;
  float* attr_out = (float*)d_out + (size_t)N_ * CX_ + 2 * (size_t)E_;
  float* bout     = (float*)d_out + (size_t)N_ * CX_ + 2 * (size_t)E_ + (size_t)E_ * CE_;
  float* xg       = (float*)d_out + (size_t)N_ * CX_ + 2 * (size_t)E_ + (size_t)E_ * CE_ + N_;

  char* w = (char*)d_ws;
  size_t off = 0;
  auto alloc = [&](size_t bytes) -> void* {
    void* p = w + off;
    off += (bytes + 511) & ~(size_t)511;
    return p;
  };
  double* bnacc = (double*)alloc(64 * 8);
  float* A      = (float*)alloc((size_t)E_ * CE_ * 4);
  float* Hb     = (float*)alloc((size_t)E_ * CE_ * 4);
  float* tgt    = (float*)alloc((size_t)N_ * CE_ * 4);
  float* hc     = (float*)alloc((size_t)N_ * CX_ * 4);
  float* h1     = (float*)alloc((size_t)N_ * CX_ * 4);
  int*   pos    = (int*)alloc((size_t)E_ * 4);   // later reused as grank
  float* tdot   = (float*)alloc((size_t)E_ * 4);
  float* score  = (float*)alloc((size_t)E_ * 4);
  int*   sel    = (int*)alloc((size_t)E_ * 4);
  int*   rp     = (int*)alloc((size_t)(N_ + 1) * 4);
  int*   cum    = (int*)alloc((size_t)N_ * 4);
  int*   comp   = (int*)alloc((size_t)N_ * 4);
  int*   lab    = (int*)alloc((size_t)N_ * 4);
  // zero-group 1: cnt,bsum,keep,xmask contiguous (each N_*4 = 512-multiple)
  int*   cnt    = (int*)alloc((size_t)N_ * 4);
  int*   bsum   = (int*)alloc((size_t)N_ * 4);
  int*   keep   = (int*)alloc((size_t)N_ * 4);
  int*   xmask  = (int*)alloc((size_t)N_ * 4);
  int*   dscan  = (int*)alloc((size_t)N_ * 4);
  // zero-group 2: bits,nbits contiguous
  unsigned int* bits  = (unsigned int*)alloc((size_t)N_ * BITW * 4);
  unsigned int* nbits = (unsigned int*)alloc((size_t)N_ * BITW * 4);
  int*   parts  = (int*)alloc(1024 * 4);
  int*   crep   = (int*)alloc((size_t)(B_ + 1) * 4);
  float* gmean  = (float*)alloc((size_t)B_ * 4);
  float* xg_raw = (float*)alloc((size_t)B_ * CX_ * 4);
  float* scale  = (float*)alloc(CE_ * 4);
  float* shift  = (float*)alloc(CE_ * 4);
  float* snorm  = (float*)alloc(4);
  if (off > ws_size) return;

  const int NB_N = gr(N_, SCAN_B);   // 45

  // ---- zero/init (consolidated) ----
  hipMemsetAsync(bnacc, 0, 64 * 8, stream);
  hipMemsetAsync(cnt, 0, (size_t)4 * N_ * 4, stream);                 // cnt,bsum,keep,xmask
  hipMemsetAsync(bits, 0, (size_t)2 * N_ * BITW * 4, stream);         // bits,nbits
  hipMemsetAsync(attr_out, 0, (size_t)E_ * CE_ * 4, stream);
  k_fillm1<<<gr(2 * E_, 256), 256, 0, stream>>>(ei0, 2 * E_);

  // ---- edge prop + mlp_e (fused) ----
  k_rowptr<<<gr(N_ + 1, 256), 256, 0, stream>>>(row, rp);
  k_pos<<<gr(E_, 256), 256, 0, stream>>>(row, col, rp, pos);
  k_tgt<<<gr(N_ * CE_, 256), 256, 0, stream>>>(eattr, pos, rp, tgt);
  k_mlp2<<<E_ / 8, 256, 0, stream>>>(eattr, tgt, row, We, be, Hb);
  k_bnstats<<<512, 256, 0, stream>>>(Hb, bnacc);
  k_bnfin<<<1, 64, 0, stream>>>(bnacc, bn_e_g, bn_e_b, S, scale, shift, snorm);
  k_bnT<<<gr(E_, 256), 256, 0, stream>>>(Hb, scale, shift, S, A, tdot);

  // ---- score / selection ----
  k_score<<<gr(E_, 256), 256, 0, stream>>>(tdot, pos, snorm, score);
  k_gmean<<<B_, 256, 0, stream>>>(score, rp, gmean);
  k_sel<<<gr(E_, 256), 256, 0, stream>>>(score, gmean, row, sel, xmask);

  // ---- connected components (LDS, early-exit) ----
  k_cc<<<B_, 256, 0, stream>>>(rp, row, col, sel, lab, cum);
  k_scan1<<<NB_N, SCAN_B, 0, stream>>>(cum, parts, N_);
  k_scan2<<<1, SCAN_B, 0, stream>>>(parts, NB_N);
  k_scan3c<<<NB_N, SCAN_B, 0, stream>>>(cum, parts, N_, crep);
  k_comp2<<<gr(N_, 256), 256, 0, stream>>>(cum, lab, batch, xmask,
                                           comp, cnt, bsum, keep, nbits);

  // ---- EGIN conv ----
  k_agg<<<N_, 128, 0, stream>>>(x, A, score, col, rp, sel, W_edge, epsp, hc);
  k_gemm128<true><<<N_ / 16, 256, 0, stream>>>(hc, W1, b1, h1);
  k_gemm128<false><<<N_ / 16, 256, 0, stream>>>(h1, W2, b2, hc);  // hc = x_conv

  // ---- pooling (+ batch_out) ----
  k_pool2<<<N_, 512, 0, stream>>>(hc, x, nbits, cnt, bsum, xmask, keep, xout, bout);

  // ---- edge coalesce ----
  k_presbits<<<gr(E_, 256), 256, 0, stream>>>(row, col, sel, comp, crep, bits);
  k_scan1d<<<NB_N, SCAN_B, 0, stream>>>(bits, dscan, parts, N_);
  k_scan2<<<1, SCAN_B, 0, stream>>>(parts, NB_N);
  k_scan3<<<NB_N, SCAN_B, 0, stream>>>(dscan, parts, N_);
  k_grank<<<gr(E_, 256), 256, 0, stream>>>(row, col, sel, comp, crep, bits, dscan, pos);
  k_attr_r<<<gr(E_, 256), 256, 0, stream>>>(A, score, pos, attr_out);
  k_eidx<<<N_, 64, 0, stream>>>(bits, dscan, cnt, bsum, crep, ei0, ei1);

  // ---- global pool + BN ----
  k_xg<<<B_, 1024, 0, stream>>>(xout, crep, xg_raw);
  k_xgbn<<<1, CX_, 0, stream>>>(xg_raw, bn_g, bn_b, xg);
}